// Round 4
// baseline (1301.886 us; speedup 1.0000x reference)
//
#include <hip/hip_runtime.h>
#include <math.h>

// ---------------------------------------------------------------------------
// ACARHead — R4: conv MFMA kernel reads B (weights) straight from global
// (L1/L2 path) instead of LDS; LDS holds only the input tile (13 KB) ->
// high occupancy. Single weight-prep kernel into wAll[t][4608][512] bf16.
// ---------------------------------------------------------------------------

typedef __bf16 bf16x8 __attribute__((ext_vector_type(8)));
typedef float  f32x4  __attribute__((ext_vector_type(4)));

#define NROI 64
#define CR   1024
#define HIDC 512
#define NCLS 60
#define PLANE (NROI * HIDC * 49)        // 1,605,632
#define ROWH 40                          // s_in row: 32 halves + 8 pad (80 B)
#define OCALL 4608                       // total oc rows in wAll
#define TAPSTR ((size_t)OCALL * 512)     // halves per tap plane
#define WL (HIDC * HIDC * 9)

__device__ __forceinline__ float bf2f(unsigned short h) {
    union { unsigned u; float f; } x; x.u = (unsigned)h << 16; return x.f;
}

// ---------- conv1 decomposition (fp32, tiny) ----------
__global__ __launch_bounds__(256) void k_Apart(
    const float* __restrict__ w1, const float* __restrict__ bg,
    float* __restrict__ A_T)
{
    const int o = blockIdx.x, p = threadIdx.x;
    const float* wr = w1 + (size_t)o * (2 * CR);
    float acc = 0.f;
    for (int c = 0; c < CR; ++c)
        acc = fmaf(wr[c], bg[c * 256 + p], acc);
    A_T[p * HIDC + o] = acc;
}

__global__ __launch_bounds__(512) void k_Bpart(
    const float* __restrict__ w1, const float* __restrict__ actor,
    float* __restrict__ B)
{
    const int n = blockIdx.x, o = threadIdx.x;
    const float* ar = actor + n * CR;
    const float* wr = w1 + (size_t)o * (2 * CR) + CR;
    float acc = 0.f;
    for (int c = 0; c < CR; ++c)
        acc = fmaf(ar[c], wr[c], acc);
    B[n * HIDC + o] = acc;
}

// ---------- single weight prep: all 9 convs -> wAll[t][4608][512] bf16 ----
// row map: [0,512) w2 | [512,2048) qkv d0 | [2048,2560) wo d0
//          [2560,4096) qkv d1 | [4096,4608) wo d1
__global__ __launch_bounds__(256) void k_prep_w(
    const float* __restrict__ w2, const float* __restrict__ wq,
    const float* __restrict__ wk, const float* __restrict__ wv,
    const float* __restrict__ wo, __bf16* __restrict__ wAll)
{
    const int bid = blockIdx.x;          // 4608
    const int tid = threadIdx.x;
    const float* src;
    if (bid < 512) src = w2 + (size_t)bid * 4608;
    else if (bid < 2048) {
        const int r = bid - 512;
        const float* b = r < 512 ? wq : (r < 1024 ? wk : wv);
        src = b + (size_t)(r & 511) * 4608;
    } else if (bid < 2560) src = wo + (size_t)(bid - 2048) * 4608;
    else if (bid < 4096) {
        const int r = bid - 2560;
        const float* b = r < 512 ? wq : (r < 1024 ? wk : wv);
        src = b + WL + (size_t)(r & 511) * 4608;
    } else src = wo + WL + (size_t)(bid - 4096) * 4608;

    __shared__ float s[4608];
    for (int i = tid; i < 4608; i += 256) s[i] = src[i];
    __syncthreads();
    unsigned* dst = (unsigned*)wAll;
    const int c = tid * 2;
#pragma unroll
    for (int t = 0; t < 9; ++t) {
        const unsigned short u0 = __builtin_bit_cast(unsigned short, (__bf16)s[c * 9 + t]);
        const unsigned short u1 = __builtin_bit_cast(unsigned short, (__bf16)s[(c + 1) * 9 + t]);
        dst[((size_t)t * TAPSTR + (size_t)bid * 512) / 2 + tid] =
            ((unsigned)u1 << 16) | u0;
    }
}

// ---------- conv2 input: relu(A_T[p][c]+B[n][c]) -> inT2[vn][81][512] -----
__global__ __launch_bounds__(256) void k_prep_in2(
    const float* __restrict__ A_T, const float* __restrict__ B,
    __bf16* __restrict__ dst)
{
    const int vn = blockIdx.x;
    const int n = vn >> 2, quad = vn & 3;
    const float b0 = B[n * HIDC + threadIdx.x];
    const float b1 = B[n * HIDC + 256 + threadIdx.x];
    for (int sp = 0; sp < 81; ++sp) {
        const int r = sp / 9, w = sp % 9;
        const int p16 = ((quad >> 1) * 7 + r) * 16 + (quad & 1) * 7 + w;
        __bf16* d = dst + ((size_t)vn * 81 + sp) * 512;
        d[threadIdx.x]       = (__bf16)fmaxf(A_T[p16 * HIDC + threadIdx.x] + b0, 0.f);
        d[256 + threadIdx.x] = (__bf16)fmaxf(A_T[p16 * HIDC + 256 + threadIdx.x] + b1, 0.f);
    }
}

// ---------- unified MFMA conv: 3x3 on 9x9 plane -> 7x7, B from global -----
// wg = 4 waves: wave w -> (vn = w&1, M-half = w>>1); wave tile 2 Mt x NT Nt.
// wg covers 2 vn x NT*16 oc.
// mode 0: qkvT bf16 [p][vn][c] (plane = oc>>9); mode 1: fp32 + resid;
// mode 2: bf16 x2 [n][196][512] relu (conv2 quadrants).
template<int NT>
__global__ __launch_bounds__(256) void k_conv_mfma(
    const __bf16* __restrict__ inT,   // [vn][81][512]
    const __bf16* __restrict__ wAll,  // [9][4608][512]
    int ocBaseGl,
    const float* __restrict__ resid,
    float* __restrict__ outf,
    __bf16* __restrict__ outb,
    int mode, int ycl)
{
    int bx = blockIdx.x, by = blockIdx.y;
    if (ycl) {  // cluster y-blocks per XCD for weight L2 residency
        const int i = by * gridDim.x + bx;
        const int xcd = i & 7, slot = i >> 3;
        const int ypx = gridDim.y >> 3;
        by = xcd * ypx + slot / gridDim.x;
        bx = slot % gridDim.x;
    }
    const int tid = threadIdx.x;
    const int w = tid >> 6, lane = tid & 63;
    const int q = lane >> 4, l16 = lane & 15;
    const int vn_l = w & 1, mh = w >> 1;
    const int vnBase = bx * 2;
    const int ocWg = by * (NT * 16);

    __shared__ __align__(16) __bf16 s_in[2 * 81 * ROWH];   // 12,960 B

    int aBase[2];
#pragma unroll
    for (int mt = 0; mt < 2; ++mt) {
        int p = (mh * 2 + mt) * 16 + l16;
        p = p > 48 ? 48 : p;
        aBase[mt] = (vn_l * 81 + (p / 7) * 9 + (p % 7)) * ROWH + q * 8;
    }
    size_t bRow[NT];
#pragma unroll
    for (int nt = 0; nt < NT; ++nt)
        bRow[nt] = (size_t)(ocBaseGl + ocWg + nt * 16 + l16) * 512 + q * 8;

    f32x4 acc[2][NT];
#pragma unroll
    for (int a = 0; a < 2; ++a)
#pragma unroll
        for (int b = 0; b < NT; ++b) acc[a][b] = (f32x4){0.f, 0.f, 0.f, 0.f};

    for (int ch = 0; ch < 16; ++ch) {
        const int c0 = ch * 32;
        __syncthreads();
        for (int idx = tid; idx < 648; idx += 256) {
            const int vnl = idx / 324, rem = idx - vnl * 324;
            const int r = rem >> 2, part = rem & 3;
            const uint4 vv = *(const uint4*)(
                inT + ((size_t)(vnBase + vnl) * 81 + r) * 512 + c0 + part * 8);
            *(uint4*)(&s_in[(vnl * 81 + r) * ROWH + part * 8]) = vv;
        }
        __syncthreads();
#pragma unroll
        for (int t = 0; t < 9; ++t) {
            const int tOffA = ((t / 3) * 9 + (t % 3)) * ROWH;
            bf16x8 bw[NT];
#pragma unroll
            for (int nt = 0; nt < NT; ++nt)
                bw[nt] = *(const bf16x8*)(wAll + (size_t)t * TAPSTR + bRow[nt] + c0);
            bf16x8 af[2];
#pragma unroll
            for (int mt = 0; mt < 2; ++mt)
                af[mt] = *(const bf16x8*)(&s_in[aBase[mt] + tOffA]);
#pragma unroll
            for (int mt = 0; mt < 2; ++mt)
#pragma unroll
                for (int nt = 0; nt < NT; ++nt)
                    acc[mt][nt] = __builtin_amdgcn_mfma_f32_16x16x32_bf16(
                        af[mt], bw[nt], acc[mt][nt], 0, 0, 0);
        }
    }

    const int vn = vnBase + vn_l;
#pragma unroll
    for (int mt = 0; mt < 2; ++mt) {
#pragma unroll
        for (int r = 0; r < 4; ++r) {
            const int p = (mh * 2 + mt) * 16 + q * 4 + r;
            if (p >= 49) continue;
#pragma unroll
            for (int nt = 0; nt < NT; ++nt) {
                const int oc = ocWg + nt * 16 + l16;
                const float v = acc[mt][nt][r];
                if (mode == 2) {
                    const int n = vn >> 2, quad = vn & 3;
                    const int p14 = ((quad >> 1) * 7 + p / 7) * 14 + (quad & 1) * 7 + p % 7;
                    outb[((size_t)n * 196 + p14) * 512 + oc] = (__bf16)fmaxf(v, 0.f);
                } else if (mode == 1) {
                    const size_t addr = ((size_t)vn * 49 + p) * 512 + oc;
                    outf[addr] = v + resid[addr];
                } else {
                    const int conv = oc >> 9;
                    outb[(size_t)conv * PLANE + ((size_t)p * 64 + vn) * 512 + (oc & 511)]
                        = (__bf16)v;
                }
            }
        }
    }
}

// ---------- fused maxpool + bf16 pack (padded) + fp32 residual ----------
__global__ __launch_bounds__(256) void k_pool_prep(
    const __bf16* __restrict__ x2, __bf16* __restrict__ inT7,
    float* __restrict__ xA)
{
    const int n = blockIdx.x / 81, sp = blockIdx.x % 81;
    const int r = sp / 9, w = sp % 9;
    __bf16* d = inT7 + ((size_t)n * 81 + sp) * 512;
    if (r < 1 || r > 7 || w < 1 || w > 7) {
        d[threadIdx.x] = (__bf16)0.f; d[256 + threadIdx.x] = (__bf16)0.f;
        return;
    }
    const int i = r - 1, j = w - 1;
#pragma unroll
    for (int k = 0; k < 2; ++k) {
        const int c = threadIdx.x + k * 256;
        float mx = -1e30f;
#pragma unroll
        for (int di = -1; di <= 1; ++di) {
            const int rr = 2 * i + di;
            if (rr < 0 || rr >= 14) continue;
#pragma unroll
            for (int dj = -1; dj <= 1; ++dj) {
                const int cc = 2 * j + dj;
                if (cc < 0 || cc >= 14) continue;
                mx = fmaxf(mx, (float)x2[((size_t)n * 196 + rr * 14 + cc) * 512 + c]);
            }
        }
        d[c] = (__bf16)mx;
        xA[((size_t)n * 49 + i * 7 + j) * 512 + c] = mx;
    }
}

// ---------- bf16 pack with zero border ----------
__global__ __launch_bounds__(256) void k_prep_feat(
    const float* __restrict__ x, __bf16* __restrict__ inT7)
{
    const int n = blockIdx.x / 81, sp = blockIdx.x % 81;
    const int r = sp / 9, w = sp % 9;
    __bf16* d = inT7 + ((size_t)n * 81 + sp) * 512;
    const bool inter = (r >= 1 && r <= 7 && w >= 1 && w <= 7);
    const int p = (r - 1) * 7 + (w - 1);
#pragma unroll
    for (int k = 0; k < 2; ++k) {
        const int c = threadIdx.x + k * 256;
        d[c] = inter ? (__bf16)x[((size_t)n * 49 + p) * 512 + c] : (__bf16)0.f;
    }
}

// ---------- attention scores + softmax over m ----------
__global__ __launch_bounds__(64) void k_att(
    const __bf16* __restrict__ qT, const __bf16* __restrict__ kT,
    float* __restrict__ att)
{
    const int n = blockIdx.x, p = blockIdx.y, m = threadIdx.x;
    __shared__ float s_q[HIDC];
    {
        const uint4 v = ((const uint4*)(qT + ((size_t)p * 64 + n) * HIDC))[m];
        const unsigned* u = (const unsigned*)&v;
#pragma unroll
        for (int j = 0; j < 4; ++j) {
            s_q[m * 8 + 2 * j]     = bf2f((unsigned short)(u[j] & 0xffff));
            s_q[m * 8 + 2 * j + 1] = bf2f((unsigned short)(u[j] >> 16));
        }
    }
    __syncthreads();
    const uint4* krow = (const uint4*)(kT + ((size_t)p * 64 + m) * HIDC);
    float acc = 0.f;
    for (int i = 0; i < 64; ++i) {
        const uint4 v = krow[i];
        const unsigned* u = (const unsigned*)&v;
#pragma unroll
        for (int j = 0; j < 4; ++j) {
            acc = fmaf(s_q[i * 8 + 2 * j],     bf2f((unsigned short)(u[j] & 0xffff)), acc);
            acc = fmaf(s_q[i * 8 + 2 * j + 1], bf2f((unsigned short)(u[j] >> 16)),    acc);
        }
    }
    acc *= 0.044194173824159216f;
    float mx = acc;
#pragma unroll
    for (int off = 32; off; off >>= 1) mx = fmaxf(mx, __shfl_xor(mx, off));
    const float e = expf(acc - mx);
    float s = e;
#pragma unroll
    for (int off = 32; off; off >>= 1) s += __shfl_xor(s, off);
    att[((size_t)n * 49 + p) * 64 + m] = e / s;
}

// ---------- virt[n][p][c] = sum_m att[n,p,m] * vT[p][m][c] ----------
__global__ __launch_bounds__(64) void k_virt(
    const float* __restrict__ att, const __bf16* __restrict__ vT,
    float* __restrict__ virt)
{
    const int n = blockIdx.x, p = blockIdx.y;
    const int c0 = threadIdx.x * 8;
    __shared__ float s_a[64];
    s_a[threadIdx.x] = att[((size_t)n * 49 + p) * 64 + threadIdx.x];
    __syncthreads();
    float acc[8];
#pragma unroll
    for (int j = 0; j < 8; ++j) acc[j] = 0.f;
    for (int m = 0; m < 64; ++m) {
        const float a = s_a[m];
        const uint4 v = *(const uint4*)(vT + ((size_t)p * 64 + m) * 512 + c0);
        const unsigned* u = (const unsigned*)&v;
#pragma unroll
        for (int j = 0; j < 4; ++j) {
            acc[2 * j]     = fmaf(a, bf2f((unsigned short)(u[j] & 0xffff)), acc[2 * j]);
            acc[2 * j + 1] = fmaf(a, bf2f((unsigned short)(u[j] >> 16)),    acc[2 * j + 1]);
        }
    }
    float* o = virt + ((size_t)n * 49 + p) * 512 + c0;
#pragma unroll
    for (int j = 0; j < 8; ++j) o[j] = acc[j];
}

// ---------- GroupNorm(1,C) stats ----------
__global__ __launch_bounds__(1024) void k_gn_stats(
    const float* __restrict__ x, float* __restrict__ stats)
{
    const int n = blockIdx.x;
    const float* xp = x + (size_t)n * (HIDC * 49);
    float s = 0.f, sq = 0.f;
    for (int i = threadIdx.x; i < HIDC * 49; i += 1024) {
        const float v = xp[i];
        s += v; sq += v * v;
    }
#pragma unroll
    for (int off = 32; off; off >>= 1) {
        s  += __shfl_xor(s, off);
        sq += __shfl_xor(sq, off);
    }
    __shared__ float rs[16], rq[16];
    const int wv = threadIdx.x >> 6, lane = threadIdx.x & 63;
    if (lane == 0) { rs[wv] = s; rq[wv] = sq; }
    __syncthreads();
    if (threadIdx.x == 0) {
        float S = 0.f, Q = 0.f;
        for (int k = 0; k < 16; ++k) { S += rs[k]; Q += rq[k]; }
        const float mean = S / (float)(HIDC * 49);
        const float var  = Q / (float)(HIDC * 49) - mean * mean;
        stats[n * 2]     = mean;
        stats[n * 2 + 1] = rsqrtf(var + 1e-5f);
    }
}

// ---------- GN affine + relu + bf16 pack ----------
__global__ __launch_bounds__(256) void k_prep_gn(
    const float* __restrict__ virt, const float* __restrict__ stats,
    const float* __restrict__ gamma, const float* __restrict__ beta,
    __bf16* __restrict__ inT7)
{
    const int n = blockIdx.x / 81, sp = blockIdx.x % 81;
    const int r = sp / 9, w = sp % 9;
    __bf16* d = inT7 + ((size_t)n * 81 + sp) * 512;
    const bool inter = (r >= 1 && r <= 7 && w >= 1 && w <= 7);
    if (!inter) {
        d[threadIdx.x] = (__bf16)0.f; d[256 + threadIdx.x] = (__bf16)0.f;
        return;
    }
    const int p = (r - 1) * 7 + (w - 1);
    const float mean = stats[n * 2], inv = stats[n * 2 + 1];
#pragma unroll
    for (int k = 0; k < 2; ++k) {
        const int c = threadIdx.x + k * 256;
        const float v = virt[((size_t)n * 49 + p) * 512 + c];
        d[c] = (__bf16)fmaxf((v - mean) * inv * gamma[c] + beta[c], 0.f);
    }
}

__global__ __launch_bounds__(512) void k_roi(
    const float* __restrict__ actor, const float* __restrict__ wfc1,
    float* __restrict__ roi)
{
    const int n = blockIdx.x, h = threadIdx.x;
    const float* ar = actor + n * CR;
    const float* wr = wfc1 + (size_t)h * CR;
    float acc = 0.f;
    for (int c = 0; c < CR; ++c)
        acc = fmaf(ar[c], wr[c], acc);
    roi[n * HIDC + h] = fmaxf(acc, 0.f);
}

// ---------- fused gap + final fc ----------
__global__ __launch_bounds__(256) void k_gapfinal(
    const float* __restrict__ x, const float* __restrict__ roi,
    const float* __restrict__ wfc2, float* __restrict__ out)
{
    const int n = blockIdx.x;
    __shared__ float s_h[HIDC];
#pragma unroll
    for (int k = 0; k < 2; ++k) {
        const int c = threadIdx.x + k * 256;
        float s = 0.f;
        for (int p = 0; p < 49; ++p) s += x[((size_t)n * 49 + p) * 512 + c];
        s_h[c] = s * (1.f / 49.f);
    }
    __syncthreads();
    const int k = threadIdx.x;
    if (k < NCLS) {
        const float* rr = roi + n * HIDC;
        const float* wr = wfc2 + (size_t)k * (2 * HIDC);
        float acc = 0.f;
        for (int j = 0; j < HIDC; ++j) acc = fmaf(rr[j], wr[j], acc);
        for (int j = 0; j < HIDC; ++j) acc = fmaf(s_h[j], wr[HIDC + j], acc);
        out[n * NCLS + k] = acc;
    }
}

// ---------------------------------------------------------------------------
extern "C" void kernel_launch(void* const* d_in, const int* in_sizes, int n_in,
                              void* d_out, int out_size, void* d_ws, size_t ws_size,
                              hipStream_t stream) {
    const float* bg    = (const float*)d_in[0];
    const float* actor = (const float*)d_in[1];
    const float* w1    = (const float*)d_in[2];
    const float* w2    = (const float*)d_in[3];
    const float* wq    = (const float*)d_in[4];
    const float* wk    = (const float*)d_in[5];
    const float* wv    = (const float*)d_in[6];
    const float* wo    = (const float*)d_in[7];
    const float* gamma = (const float*)d_in[8];
    const float* beta  = (const float*)d_in[9];
    const float* wfc1  = (const float*)d_in[10];
    const float* wfc2  = (const float*)d_in[11];
    float* out = (float*)d_out;
    float* ws  = (float*)d_ws;

    // ---- fp32 regions (3,639,472 floats) ----
    float* A_T   = ws;                        // 131,072
    float* Bp    = A_T + 131072;              // 32,768
    float* xA    = Bp + 32768;                // PLANE
    float* xB    = xA + PLANE;                // PLANE
    float* att   = xB + PLANE;                // 200,704
    float* stats = att + 200704;              // 128
    float* roi   = stats + 128;               // 32,768
    float* fend  = roi + 32768;
    // ---- bf16 regions ----
    __bf16* x2h  = (__bf16*)fend;             // 64*196*512 = 6,422,528 halves
    float*  virt = (float*)x2h;               // aliases x2 (dead after pool)
    __bf16* inT2 = x2h + 6422528;             // 256*81*512 = 10,616,832
    __bf16* qkvT = inT2;                      // aliases inT2 (dead after conv2)
    __bf16* inT7 = inT2 + 10616832;           // 64*81*512  = 2,654,208
    __bf16* wAll = inT7 + 2654208;            // 9*4608*512 = 21,233,664

    k_Apart<<<512, 256, 0, stream>>>(w1, bg, A_T);
    k_Bpart<<<64, 512, 0, stream>>>(w1, actor, Bp);
    k_prep_w<<<4608, 256, 0, stream>>>(w2, wq, wk, wv, wo, wAll);
    k_prep_in2<<<256, 256, 0, stream>>>(A_T, Bp, inT2);

    // conv2: 256 quadrant-planes, oc 512 -> grid 128 x 8 = 1024 wgs
    k_conv_mfma<4><<<dim3(128, 8), 256, 0, stream>>>(
        inT2, wAll, 0, nullptr, nullptr, x2h, 2, 0);
    k_pool_prep<<<64 * 81, 256, 0, stream>>>(x2h, inT7, xA);

    float* xin = xA;
    float* xout = xB;
    for (int d = 0; d < 2; ++d) {
        if (d > 0)
            k_prep_feat<<<64 * 81, 256, 0, stream>>>(xin, inT7);
        // fused qkv: oc 1536 -> grid 32 x 24 = 768 wgs, XCD y-clustered
        k_conv_mfma<4><<<dim3(32, 24), 256, 0, stream>>>(
            inT7, wAll, 512 + d * 2048, nullptr, nullptr, qkvT, 0, 1);
        k_att<<<dim3(64, 49), 64, 0, stream>>>(qkvT, qkvT + PLANE, att);
        k_virt<<<dim3(64, 49), 64, 0, stream>>>(att, qkvT + 2 * PLANE, virt);
        k_gn_stats<<<64, 1024, 0, stream>>>(virt, stats);
        k_prep_gn<<<64 * 81, 256, 0, stream>>>(virt, stats,
                                               gamma + d * HIDC, beta + d * HIDC, inT7);
        // wo + residual: oc 512, NT=2 -> grid 32 x 16 = 512 wgs
        k_conv_mfma<2><<<dim3(32, 16), 256, 0, stream>>>(
            inT7, wAll, 2048 + d * 2048, xin, xout, nullptr, 1, 0);
        float* t = xin; xin = xout; xout = t;
    }
    k_roi<<<64, 512, 0, stream>>>(actor, wfc1, roi);
    k_gapfinal<<<64, 256, 0, stream>>>(xin, roi, wfc2, out);
}

// Round 5
// 881.574 us; speedup vs baseline: 1.4768x; 1.4768x over previous
//
#include <hip/hip_runtime.h>
#include <math.h>

// ---------------------------------------------------------------------------
// ACARHead — R5: revert to LDS-staged weights (R4's global-B was latency-
// bound, MfmaUtil 11%). Conv: VN=4/NT=8 with 3-tap s_w staging via
// global_load_lds from pre-swizzled wAll. Tail: 1 prep_w dispatch, fused
// att+virt, wo epilogue emits next layer's bf16 input, fused gap+final.
// ---------------------------------------------------------------------------

typedef __bf16 bf16x8 __attribute__((ext_vector_type(8)));
typedef float  f32x4  __attribute__((ext_vector_type(4)));

#define NROI 64
#define CR   1024
#define HIDC 512
#define NCLS 60
#define PLANE (NROI * HIDC * 49)        // 1,605,632
#define ROWH 40                          // s_in row: 32 halves + 8 pad (80 B)
#define OCALL 4608
#define TAPSTR ((size_t)OCALL * 512)
#define WL (HIDC * HIDC * 9)

#if defined(__has_builtin)
#  if __has_builtin(__builtin_amdgcn_global_load_lds)
#    define HAVE_GLL 1
#  endif
#endif

__device__ __forceinline__ void stage16(const void* g, void* lds_base, int lane) {
#ifdef HAVE_GLL
    __builtin_amdgcn_global_load_lds(
        (const __attribute__((address_space(1))) unsigned int*)g,
        (__attribute__((address_space(3))) unsigned int*)lds_base, 16, 0, 0);
#else
    *(uint4*)((char*)lds_base + lane * 16) = *(const uint4*)g;
#endif
}

__device__ __forceinline__ float bf2f(unsigned short h) {
    union { unsigned u; float f; } x; x.u = (unsigned)h << 16; return x.f;
}

// ---------- conv1 decomposition ----------
__global__ __launch_bounds__(256) void k_Apart(
    const float* __restrict__ w1, const float* __restrict__ bg,
    float* __restrict__ A_T)
{
    const int o = blockIdx.x, p = threadIdx.x;
    const float* wr = w1 + (size_t)o * (2 * CR);
    float acc = 0.f;
    for (int c = 0; c < CR; ++c)
        acc = fmaf(wr[c], bg[c * 256 + p], acc);
    A_T[p * HIDC + o] = acc;
}

__global__ __launch_bounds__(512) void k_Bpart(
    const float* __restrict__ w1, const float* __restrict__ actor,
    float* __restrict__ B)
{
    const int n = blockIdx.x, o = threadIdx.x;
    const float* ar = actor + n * CR;
    const float* wr = w1 + (size_t)o * (2 * CR) + CR;
    float acc = 0.f;
    for (int c = 0; c < CR; ++c)
        acc = fmaf(ar[c], wr[c], acc);
    B[n * HIDC + o] = acc;
}

// ---------- single weight prep: all 9 convs -> swizzled wAll[t][4608][512] -
// row map: [0,512) w2 | [512,2048) qkv d0 | [2048,2560) wo d0
//          [2560,4096) qkv d1 | [4096,4608) wo d1
// swizzle: element (oc,c) stored at part' = ((c>>3)&3) ^ ((oc>>1)&3)
__global__ __launch_bounds__(256) void k_prep_w(
    const float* __restrict__ w2, const float* __restrict__ wq,
    const float* __restrict__ wk, const float* __restrict__ wv,
    const float* __restrict__ wo, __bf16* __restrict__ wAll)
{
    const int bid = blockIdx.x;          // 4608 = oc row
    const int tid = threadIdx.x;
    const float* src;
    if (bid < 512) src = w2 + (size_t)bid * 4608;
    else if (bid < 2048) {
        const int r = bid - 512;
        const float* b = r < 512 ? wq : (r < 1024 ? wk : wv);
        src = b + (size_t)(r & 511) * 4608;
    } else if (bid < 2560) src = wo + (size_t)(bid - 2048) * 4608;
    else if (bid < 4096) {
        const int r = bid - 2560;
        const float* b = r < 512 ? wq : (r < 1024 ? wk : wv);
        src = b + WL + (size_t)(r & 511) * 4608;
    } else src = wo + WL + (size_t)(bid - 4096) * 4608;

    __shared__ float s[4608];
    for (int i = tid; i < 4608; i += 256) s[i] = src[i];
    __syncthreads();
    unsigned* dst = (unsigned*)wAll;
    const int c = tid * 2;
    const int swz = ((c >> 3) & 3) ^ ((bid >> 1) & 3);
    const size_t cidx = (size_t)(c >> 5) * 32 + swz * 8 + (c & 7);
#pragma unroll
    for (int t = 0; t < 9; ++t) {
        const unsigned short u0 = __builtin_bit_cast(unsigned short, (__bf16)s[c * 9 + t]);
        const unsigned short u1 = __builtin_bit_cast(unsigned short, (__bf16)s[(c + 1) * 9 + t]);
        dst[((size_t)t * TAPSTR + (size_t)bid * 512 + cidx) / 2] =
            ((unsigned)u1 << 16) | u0;
    }
}

// ---------- conv2 input: relu(A_T[p][c]+B[n][c]) -> inT2[vn][81][512] -----
__global__ __launch_bounds__(256) void k_prep_in2(
    const float* __restrict__ A_T, const float* __restrict__ B,
    __bf16* __restrict__ dst)
{
    const int vn = blockIdx.x;
    const int n = vn >> 2, quad = vn & 3;
    const float b0 = B[n * HIDC + threadIdx.x];
    const float b1 = B[n * HIDC + 256 + threadIdx.x];
    for (int sp = 0; sp < 81; ++sp) {
        const int r = sp / 9, w = sp % 9;
        const int p16 = ((quad >> 1) * 7 + r) * 16 + (quad & 1) * 7 + w;
        __bf16* d = dst + ((size_t)vn * 81 + sp) * 512;
        d[threadIdx.x]       = (__bf16)fmaxf(A_T[p16 * HIDC + threadIdx.x] + b0, 0.f);
        d[256 + threadIdx.x] = (__bf16)fmaxf(A_T[p16 * HIDC + 256 + threadIdx.x] + b1, 0.f);
    }
}

// ---------- unified MFMA conv, 3-tap-group LDS weight staging ----------
// wg: VN vn x NT*16 oc. VN=4: wave=vn, MT=4. VN=2: wave=(vn,mh), MT=2.
// mode 0: qkvT bf16 [p][vn][c]; mode 1: fp32 +resid (+optional inT7 interior);
// mode 2: bf16 x2 [n][196][512] relu (conv2 quadrants).
template<int VN, int NT>
__global__ __launch_bounds__(256, 2) void k_conv_mfma(
    const __bf16* __restrict__ inT,   // [vn][81][512]
    const __bf16* __restrict__ wAll,  // swizzled [9][4608][512]
    int ocBaseGl,
    const float* __restrict__ resid,
    float* __restrict__ outf,
    __bf16* __restrict__ outb,
    __bf16* __restrict__ inT7out,
    int mode)
{
    constexpr int MT = (VN == 4) ? 4 : 2;
    constexpr int GRP = NT * 16 * 4;          // lane-slots per tap (row,part)
    constexpr int IPW = (3 * GRP) / 256;      // stage16 instrs per wave
    const int tid = threadIdx.x;
    const int w = tid >> 6, lane = tid & 63;
    const int q = lane >> 4, l16 = lane & 15;
    const int vn_l = (VN == 4) ? w : (w & 1);
    const int mh   = (VN == 4) ? 0 : (w >> 1);
    const int vnBase = blockIdx.x * VN;
    const int ocWg = blockIdx.y * (NT * 16);

    __shared__ __align__(16) __bf16 s_w[3 * NT * 16 * 32];
    __shared__ __align__(16) __bf16 s_in[VN * 81 * ROWH];

    const int bBase = l16 * 32 + ((q ^ ((l16 >> 1) & 3)) << 3);
    int aBase[MT];
#pragma unroll
    for (int mt = 0; mt < MT; ++mt) {
        int p = (mh * MT + mt) * 16 + l16;
        p = p > 48 ? 48 : p;
        aBase[mt] = (vn_l * 81 + (p / 7) * 9 + (p % 7)) * ROWH + q * 8;
    }

    f32x4 acc[MT][NT];
#pragma unroll
    for (int a = 0; a < MT; ++a)
#pragma unroll
        for (int b = 0; b < NT; ++b) acc[a][b] = (f32x4){0.f, 0.f, 0.f, 0.f};

    for (int ch = 0; ch < 16; ++ch) {
        const int c0 = ch * 32;
#pragma unroll 1
        for (int kh = 0; kh < 3; ++kh) {
            __syncthreads();
            // --- weights: tap row kh (3 taps), async global->LDS ---
#pragma unroll
            for (int i = 0; i < IPW; ++i) {
                const int s0 = (w * IPW + i) * 64;
                const int s = s0 + lane;
                const int tl = s / GRP;
                const int rem = s - tl * GRP;
                const int row = rem >> 2, part = rem & 3;
                const __bf16* g = wAll +
                    ((size_t)(kh * 3 + tl) * OCALL + ocBaseGl + ocWg + row) * 512
                    + c0 + part * 8;
                stage16(g, (char*)s_w + (size_t)s0 * 16, lane);
            }
            // --- input: once per chunk, alongside group 0 ---
            if (kh == 0) {
                for (int idx = tid; idx < VN * 324; idx += 256) {
                    const int vnl = idx / 324, rem = idx - vnl * 324;
                    const int r = rem >> 2, part = rem & 3;
                    const uint4 vv = *(const uint4*)(
                        inT + ((size_t)(vnBase + vnl) * 81 + r) * 512 + c0 + part * 8);
                    *(uint4*)(&s_in[(vnl * 81 + r) * ROWH + part * 8]) = vv;
                }
            }
            __syncthreads();
#pragma unroll
            for (int kw = 0; kw < 3; ++kw) {
                const int tOffA = (kh * 9 + kw) * ROWH;
                bf16x8 bw[NT];
#pragma unroll
                for (int nt = 0; nt < NT; ++nt)
                    bw[nt] = *(const bf16x8*)(&s_w[(kw * NT + nt) * 16 * 32 + bBase]);
                bf16x8 af[MT];
#pragma unroll
                for (int mt = 0; mt < MT; ++mt)
                    af[mt] = *(const bf16x8*)(&s_in[aBase[mt] + tOffA]);
#pragma unroll
                for (int mt = 0; mt < MT; ++mt)
#pragma unroll
                    for (int nt = 0; nt < NT; ++nt)
                        acc[mt][nt] = __builtin_amdgcn_mfma_f32_16x16x32_bf16(
                            af[mt], bw[nt], acc[mt][nt], 0, 0, 0);
            }
        }
    }

    const int vn = vnBase + vn_l;
#pragma unroll
    for (int mt = 0; mt < MT; ++mt) {
#pragma unroll
        for (int r = 0; r < 4; ++r) {
            const int p = (mh * MT + mt) * 16 + q * 4 + r;
            if (p >= 49) continue;
#pragma unroll
            for (int nt = 0; nt < NT; ++nt) {
                const int oc = ocWg + nt * 16 + l16;
                const float v = acc[mt][nt][r];
                if (mode == 2) {
                    const int n = vn >> 2, quad = vn & 3;
                    const int p14 = ((quad >> 1) * 7 + p / 7) * 14 + (quad & 1) * 7 + p % 7;
                    outb[((size_t)n * 196 + p14) * 512 + oc] = (__bf16)fmaxf(v, 0.f);
                } else if (mode == 1) {
                    const size_t addr = ((size_t)vn * 49 + p) * 512 + oc;
                    const float res = v + resid[addr];
                    outf[addr] = res;
                    if (inT7out) {
                        const int sp = (p / 7 + 1) * 9 + (p % 7 + 1);
                        inT7out[((size_t)vn * 81 + sp) * 512 + oc] = (__bf16)res;
                    }
                } else {
                    const int conv = oc >> 9;
                    outb[(size_t)conv * PLANE + ((size_t)p * 64 + vn) * 512 + (oc & 511)]
                        = (__bf16)v;
                }
            }
        }
    }
}

// ---------- fused maxpool + bf16 pack (interior) + fp32 residual ----------
__global__ __launch_bounds__(256) void k_pool_prep(
    const __bf16* __restrict__ x2, __bf16* __restrict__ inT7,
    float* __restrict__ xA)
{
    const int b = blockIdx.x;                 // 64*49
    const int n = b / 49, p = b % 49;
    const int i = p / 7, j = p % 7;
    const int sp = (i + 1) * 9 + (j + 1);
#pragma unroll
    for (int k = 0; k < 2; ++k) {
        const int c = threadIdx.x + k * 256;
        float mx = -1e30f;
#pragma unroll
        for (int di = -1; di <= 1; ++di) {
            const int rr = 2 * i + di;
            if (rr < 0 || rr >= 14) continue;
#pragma unroll
            for (int dj = -1; dj <= 1; ++dj) {
                const int cc = 2 * j + dj;
                if (cc < 0 || cc >= 14) continue;
                mx = fmaxf(mx, (float)x2[((size_t)n * 196 + rr * 14 + cc) * 512 + c]);
            }
        }
        inT7[((size_t)n * 81 + sp) * 512 + c] = (__bf16)mx;
        xA[((size_t)n * 49 + p) * 512 + c] = mx;
    }
}

// ---------- fused attention: scores + softmax + virt ----------
__global__ __launch_bounds__(64) void k_attvirt(
    const __bf16* __restrict__ qT, const __bf16* __restrict__ kT,
    const __bf16* __restrict__ vT, float* __restrict__ virt)
{
    const int n = blockIdx.x, p = blockIdx.y, m = threadIdx.x;
    __shared__ float s_q[HIDC];
    {
        const uint4 v = ((const uint4*)(qT + ((size_t)p * 64 + n) * HIDC))[m];
        const unsigned* u = (const unsigned*)&v;
#pragma unroll
        for (int j = 0; j < 4; ++j) {
            s_q[m * 8 + 2 * j]     = bf2f((unsigned short)(u[j] & 0xffff));
            s_q[m * 8 + 2 * j + 1] = bf2f((unsigned short)(u[j] >> 16));
        }
    }
    __syncthreads();
    const uint4* krow = (const uint4*)(kT + ((size_t)p * 64 + m) * HIDC);
    float acc = 0.f;
    for (int i = 0; i < 64; ++i) {
        const uint4 v = krow[i];
        const unsigned* u = (const unsigned*)&v;
#pragma unroll
        for (int j = 0; j < 4; ++j) {
            acc = fmaf(s_q[i * 8 + 2 * j],     bf2f((unsigned short)(u[j] & 0xffff)), acc);
            acc = fmaf(s_q[i * 8 + 2 * j + 1], bf2f((unsigned short)(u[j] >> 16)),    acc);
        }
    }
    acc *= 0.044194173824159216f;
    float mx = acc;
#pragma unroll
    for (int off = 32; off; off >>= 1) mx = fmaxf(mx, __shfl_xor(mx, off));
    const float e = expf(acc - mx);
    float s = e;
#pragma unroll
    for (int off = 32; off; off >>= 1) s += __shfl_xor(s, off);
    __shared__ float s_a[64];
    s_a[m] = e / s;
    __syncthreads();
    const int c0 = m * 8;
    float av[8];
#pragma unroll
    for (int j = 0; j < 8; ++j) av[j] = 0.f;
    for (int mm = 0; mm < 64; ++mm) {
        const float a = s_a[mm];
        const uint4 v = *(const uint4*)(vT + ((size_t)p * 64 + mm) * HIDC + c0);
        const unsigned* u = (const unsigned*)&v;
#pragma unroll
        for (int j = 0; j < 4; ++j) {
            av[2 * j]     = fmaf(a, bf2f((unsigned short)(u[j] & 0xffff)), av[2 * j]);
            av[2 * j + 1] = fmaf(a, bf2f((unsigned short)(u[j] >> 16)),    av[2 * j + 1]);
        }
    }
    float* o = virt + ((size_t)n * 49 + p) * 512 + c0;
#pragma unroll
    for (int j = 0; j < 8; ++j) o[j] = av[j];
}

// ---------- GroupNorm(1,C) stats ----------
__global__ __launch_bounds__(1024) void k_gn_stats(
    const float* __restrict__ x, float* __restrict__ stats)
{
    const int n = blockIdx.x;
    const float* xp = x + (size_t)n * (HIDC * 49);
    float s = 0.f, sq = 0.f;
    for (int i = threadIdx.x; i < HIDC * 49; i += 1024) {
        const float v = xp[i];
        s += v; sq += v * v;
    }
#pragma unroll
    for (int off = 32; off; off >>= 1) {
        s  += __shfl_xor(s, off);
        sq += __shfl_xor(sq, off);
    }
    __shared__ float rs[16], rq[16];
    const int wv = threadIdx.x >> 6, lane = threadIdx.x & 63;
    if (lane == 0) { rs[wv] = s; rq[wv] = sq; }
    __syncthreads();
    if (threadIdx.x == 0) {
        float S = 0.f, Q = 0.f;
        for (int k = 0; k < 16; ++k) { S += rs[k]; Q += rq[k]; }
        const float mean = S / (float)(HIDC * 49);
        const float var  = Q / (float)(HIDC * 49) - mean * mean;
        stats[n * 2]     = mean;
        stats[n * 2 + 1] = rsqrtf(var + 1e-5f);
    }
}

// ---------- GN affine + relu + bf16 pack (interior only) ----------
__global__ __launch_bounds__(256) void k_prep_gn(
    const float* __restrict__ virt, const float* __restrict__ stats,
    const float* __restrict__ gamma, const float* __restrict__ beta,
    __bf16* __restrict__ inT7)
{
    const int b = blockIdx.x;                 // 64*49
    const int n = b / 49, p = b % 49;
    const int sp = (p / 7 + 1) * 9 + (p % 7 + 1);
    const float mean = stats[n * 2], inv = stats[n * 2 + 1];
#pragma unroll
    for (int k = 0; k < 2; ++k) {
        const int c = threadIdx.x + k * 256;
        const float v = virt[((size_t)n * 49 + p) * 512 + c];
        inT7[((size_t)n * 81 + sp) * 512 + c] =
            (__bf16)fmaxf((v - mean) * inv * gamma[c] + beta[c], 0.f);
    }
}

__global__ __launch_bounds__(512) void k_roi(
    const float* __restrict__ actor, const float* __restrict__ wfc1,
    float* __restrict__ roi)
{
    const int n = blockIdx.x, h = threadIdx.x;
    const float* ar = actor + n * CR;
    const float* wr = wfc1 + (size_t)h * CR;
    float acc = 0.f;
    for (int c = 0; c < CR; ++c)
        acc = fmaf(ar[c], wr[c], acc);
    roi[n * HIDC + h] = fmaxf(acc, 0.f);
}

__global__ __launch_bounds__(256) void k_gapfinal(
    const float* __restrict__ x, const float* __restrict__ roi,
    const float* __restrict__ wfc2, float* __restrict__ out)
{
    const int n = blockIdx.x;
    __shared__ float s_h[HIDC];
#pragma unroll
    for (int k = 0; k < 2; ++k) {
        const int c = threadIdx.x + k * 256;
        float s = 0.f;
        for (int p = 0; p < 49; ++p) s += x[((size_t)n * 49 + p) * 512 + c];
        s_h[c] = s * (1.f / 49.f);
    }
    __syncthreads();
    const int k = threadIdx.x;
    if (k < NCLS) {
        const float* rr = roi + n * HIDC;
        const float* wr = wfc2 + (size_t)k * (2 * HIDC);
        float acc = 0.f;
        for (int j = 0; j < HIDC; ++j) acc = fmaf(rr[j], wr[j], acc);
        for (int j = 0; j < HIDC; ++j) acc = fmaf(s_h[j], wr[HIDC + j], acc);
        out[n * NCLS + k] = acc;
    }
}

// ---------------------------------------------------------------------------
extern "C" void kernel_launch(void* const* d_in, const int* in_sizes, int n_in,
                              void* d_out, int out_size, void* d_ws, size_t ws_size,
                              hipStream_t stream) {
    const float* bg    = (const float*)d_in[0];
    const float* actor = (const float*)d_in[1];
    const float* w1    = (const float*)d_in[2];
    const float* w2    = (const float*)d_in[3];
    const float* wq    = (const float*)d_in[4];
    const float* wk    = (const float*)d_in[5];
    const float* wv    = (const float*)d_in[6];
    const float* wo    = (const float*)d_in[7];
    const float* gamma = (const float*)d_in[8];
    const float* beta  = (const float*)d_in[9];
    const float* wfc1  = (const float*)d_in[10];
    const float* wfc2  = (const float*)d_in[11];
    float* out = (float*)d_out;
    float* ws  = (float*)d_ws;

    // ---- fp32 regions ----
    float* A_T   = ws;                        // 131,072
    float* Bp    = A_T + 131072;              // 32,768
    float* xA    = Bp + 32768;                // PLANE
    float* xB    = xA + PLANE;                // PLANE
    float* stats = xB + PLANE;                // 128
    float* roi   = stats + 128;               // 32,768
    float* fend  = roi + 32768;
    // ---- bf16 regions ----
    __bf16* x2h  = (__bf16*)fend;             // 64*196*512 = 6,422,528 halves
    float*  virt = (float*)x2h;               // aliases x2h (dead after pool)
    __bf16* inT2 = x2h + 6422528;             // 256*81*512 = 10,616,832
    __bf16* qkvT = inT2;                      // aliases inT2 (dead after conv2)
    __bf16* inT7 = inT2 + 10616832;           // 64*81*512  = 2,654,208
    __bf16* wAll = inT7 + 2654208;            // 9*4608*512 = 21,233,664

    k_Apart<<<512, 256, 0, stream>>>(w1, bg, A_T);
    k_Bpart<<<64, 512, 0, stream>>>(w1, actor, Bp);
    k_prep_w<<<4608, 256, 0, stream>>>(w2, wq, wk, wv, wv == wk ? wk : wo, wAll);
    k_prep_in2<<<256, 256, 0, stream>>>(A_T, Bp, inT2);
    // zero inT7 once per call: borders stay zero across both layers
    hipMemsetAsync(inT7, 0, (size_t)64 * 81 * 512 * sizeof(__bf16), stream);

    // conv2: 256 quadrant-planes, oc 512 -> grid 64 x 4 = 256 wgs
    k_conv_mfma<4, 8><<<dim3(64, 4), 256, 0, stream>>>(
        inT2, wAll, 0, nullptr, nullptr, x2h, nullptr, 2);
    k_pool_prep<<<64 * 49, 256, 0, stream>>>(x2h, inT7, xA);

    float* xin = xA;
    float* xout = xB;
    for (int d = 0; d < 2; ++d) {
        // fused qkv: oc 1536 -> grid 16 x 12 = 192 wgs
        k_conv_mfma<4, 8><<<dim3(16, 12), 256, 0, stream>>>(
            inT7, wAll, 512 + d * 2048, nullptr, nullptr, qkvT, nullptr, 0);
        k_attvirt<<<dim3(64, 49), 64, 0, stream>>>(
            qkvT, qkvT + PLANE, qkvT + 2 * PLANE, virt);
        k_gn_stats<<<64, 1024, 0, stream>>>(virt, stats);
        k_prep_gn<<<64 * 49, 256, 0, stream>>>(virt, stats,
                                               gamma + d * HIDC, beta + d * HIDC, inT7);
        // wo + residual: grid 32 x 8 = 256 wgs; writes next layer's inT7
        k_conv_mfma<2, 4><<<dim3(32, 8), 256, 0, stream>>>(
            inT7, wAll, 2048 + d * 2048, xin, xout, nullptr,
            d == 0 ? inT7 : nullptr, 1);
        float* t = xin; xin = xout; xout = t;
    }
    k_roi<<<64, 512, 0, stream>>>(actor, wfc1, roi);
    k_gapfinal<<<64, 256, 0, stream>>>(xin, roi, wfc2, out);
}

// Round 6
// 764.754 us; speedup vs baseline: 1.7024x; 1.1528x over previous
//
#include <hip/hip_runtime.h>
#include <math.h>

// ---------------------------------------------------------------------------
// ACARHead — R6: occupancy-first MFMA conv. wg = VN2 x 64oc (MT2/NT4),
// all-9-tap s_w (2 barriers/chunk), 3 wg/CU, wide grids (>=512 wgs).
// Weights staged via global_load_lds from pre-swizzled wAll.
// ---------------------------------------------------------------------------

typedef __bf16 bf16x8 __attribute__((ext_vector_type(8)));
typedef float  f32x4  __attribute__((ext_vector_type(4)));

#define NROI 64
#define CR   1024
#define HIDC 512
#define NCLS 60
#define PLANE (NROI * HIDC * 49)        // 1,605,632
#define ROWH 40                          // s_in row: 32 halves + 8 pad (80 B)
#define OCALL 4608
#define TAPSTR ((size_t)OCALL * 512)
#define WL (HIDC * HIDC * 9)

#if defined(__has_builtin)
#  if __has_builtin(__builtin_amdgcn_global_load_lds)
#    define HAVE_GLL 1
#  endif
#endif

__device__ __forceinline__ void stage16(const void* g, void* lds_base, int lane) {
#ifdef HAVE_GLL
    __builtin_amdgcn_global_load_lds(
        (const __attribute__((address_space(1))) unsigned int*)g,
        (__attribute__((address_space(3))) unsigned int*)lds_base, 16, 0, 0);
#else
    *(uint4*)((char*)lds_base + lane * 16) = *(const uint4*)g;
#endif
}

__device__ __forceinline__ float bf2f(unsigned short h) {
    union { unsigned u; float f; } x; x.u = (unsigned)h << 16; return x.f;
}

// ---------- conv1 decomposition ----------
__global__ __launch_bounds__(256) void k_Apart(
    const float* __restrict__ w1, const float* __restrict__ bg,
    float* __restrict__ A_T)
{
    const int o = blockIdx.x, p = threadIdx.x;
    const float* wr = w1 + (size_t)o * (2 * CR);
    float acc = 0.f;
    for (int c = 0; c < CR; ++c)
        acc = fmaf(wr[c], bg[c * 256 + p], acc);
    A_T[p * HIDC + o] = acc;
}

__global__ __launch_bounds__(512) void k_Bpart(
    const float* __restrict__ w1, const float* __restrict__ actor,
    float* __restrict__ B)
{
    const int n = blockIdx.x, o = threadIdx.x;
    const float* ar = actor + n * CR;
    const float* wr = w1 + (size_t)o * (2 * CR) + CR;
    float acc = 0.f;
    for (int c = 0; c < CR; ++c)
        acc = fmaf(ar[c], wr[c], acc);
    B[n * HIDC + o] = acc;
}

// ---------- single weight prep: all 9 convs -> swizzled wAll[t][4608][512] -
// row map: [0,512) w2 | [512,2048) qkv d0 | [2048,2560) wo d0
//          [2560,4096) qkv d1 | [4096,4608) wo d1
// swizzle: element (oc,c) stored at part' = ((c>>3)&3) ^ ((oc>>1)&3)
__global__ __launch_bounds__(256) void k_prep_w(
    const float* __restrict__ w2, const float* __restrict__ wq,
    const float* __restrict__ wk, const float* __restrict__ wv,
    const float* __restrict__ wo, __bf16* __restrict__ wAll)
{
    const int bid = blockIdx.x;          // 4608 = oc row
    const int tid = threadIdx.x;
    const float* src;
    if (bid < 512) src = w2 + (size_t)bid * 4608;
    else if (bid < 2048) {
        const int r = bid - 512;
        const float* b = r < 512 ? wq : (r < 1024 ? wk : wv);
        src = b + (size_t)(r & 511) * 4608;
    } else if (bid < 2560) src = wo + (size_t)(bid - 2048) * 4608;
    else if (bid < 4096) {
        const int r = bid - 2560;
        const float* b = r < 512 ? wq : (r < 1024 ? wk : wv);
        src = b + WL + (size_t)(r & 511) * 4608;
    } else src = wo + WL + (size_t)(bid - 4096) * 4608;

    __shared__ float s[4608];
    for (int i = tid; i < 4608; i += 256) s[i] = src[i];
    __syncthreads();
    unsigned* dst = (unsigned*)wAll;
    const int c = tid * 2;
    const int swz = ((c >> 3) & 3) ^ ((bid >> 1) & 3);
    const size_t cidx = (size_t)(c >> 5) * 32 + swz * 8 + (c & 7);
#pragma unroll
    for (int t = 0; t < 9; ++t) {
        const unsigned short u0 = __builtin_bit_cast(unsigned short, (__bf16)s[c * 9 + t]);
        const unsigned short u1 = __builtin_bit_cast(unsigned short, (__bf16)s[(c + 1) * 9 + t]);
        dst[((size_t)t * TAPSTR + (size_t)bid * 512 + cidx) / 2] =
            ((unsigned)u1 << 16) | u0;
    }
}

// ---------- conv2 input: relu(A_T[p][c]+B[n][c]) -> inT2[vn][81][512] -----
__global__ __launch_bounds__(256) void k_prep_in2(
    const float* __restrict__ A_T, const float* __restrict__ B,
    __bf16* __restrict__ dst)
{
    const int vn = blockIdx.x;
    const int n = vn >> 2, quad = vn & 3;
    const float b0 = B[n * HIDC + threadIdx.x];
    const float b1 = B[n * HIDC + 256 + threadIdx.x];
    for (int sp = 0; sp < 81; ++sp) {
        const int r = sp / 9, w = sp % 9;
        const int p16 = ((quad >> 1) * 7 + r) * 16 + (quad & 1) * 7 + w;
        __bf16* d = dst + ((size_t)vn * 81 + sp) * 512;
        d[threadIdx.x]       = (__bf16)fmaxf(A_T[p16 * HIDC + threadIdx.x] + b0, 0.f);
        d[256 + threadIdx.x] = (__bf16)fmaxf(A_T[p16 * HIDC + 256 + threadIdx.x] + b1, 0.f);
    }
}

// ---------- unified MFMA conv ----------
// VN vn per wg, oc 64 per wg (NT=4).
// VN==2: wave=(vn w&1, mh w>>1), MT=2.  VN==1: wave=mh, MT=1.
// mode 0: qkvT bf16 [p][vn][c]; mode 1: fp32 +resid (+optional inT7 interior);
// mode 2: bf16 x2 [n][196][512] relu (conv2 quadrants).
template<int VN>
__global__ __launch_bounds__(256, 3) void k_conv_mfma(
    const __bf16* __restrict__ inT,   // [vn][81][512]
    const __bf16* __restrict__ wAll,  // swizzled [9][4608][512]
    int ocBaseGl,
    const float* __restrict__ resid,
    float* __restrict__ outf,
    __bf16* __restrict__ outb,
    __bf16* __restrict__ inT7out,
    int mode)
{
    constexpr int MT = (VN == 2) ? 2 : 1;
    const int tid = threadIdx.x;
    const int w = tid >> 6, lane = tid & 63;
    const int q = lane >> 4, l16 = lane & 15;
    const int vn_l = (VN == 2) ? (w & 1) : 0;
    const int mh   = (VN == 2) ? (w >> 1) : w;
    const int vnBase = blockIdx.x * VN;
    const int ocWg = blockIdx.y * 64;

    __shared__ __align__(16) __bf16 s_w[9 * 64 * 32];      // 36,864 B
    __shared__ __align__(16) __bf16 s_in[VN * 81 * ROWH];  // VN2: 12,960 B

    const int bSwz = (q ^ ((l16 >> 1) & 3)) << 3;
    int aBase[MT];
#pragma unroll
    for (int mt = 0; mt < MT; ++mt) {
        int p = (mh * MT + mt) * 16 + l16;
        p = p > 48 ? 48 : p;
        aBase[mt] = (vn_l * 81 + (p / 7) * 9 + (p % 7)) * ROWH + q * 8;
    }

    f32x4 acc[MT][4];
#pragma unroll
    for (int a = 0; a < MT; ++a)
#pragma unroll
        for (int b = 0; b < 4; ++b) acc[a][b] = (f32x4){0.f, 0.f, 0.f, 0.f};

    for (int ch = 0; ch < 16; ++ch) {
        const int c0 = ch * 32;
        __syncthreads();
        // --- weights: all 9 taps async global->LDS (9 insts/wave) ---
#pragma unroll
        for (int i = 0; i < 9; ++i) {
            const int s0 = (w * 9 + i) * 64;
            const int s = s0 + lane;
            const int t = s >> 8;
            const int rem = s & 255;
            const int row = rem >> 2, part = rem & 3;
            const __bf16* g = wAll + (size_t)t * TAPSTR
                + (size_t)(ocBaseGl + ocWg + row) * 512 + c0 + part * 8;
            stage16(g, (char*)s_w + (size_t)s0 * 16, lane);
        }
        // --- input plane(s) ---
        for (int idx = tid; idx < VN * 324; idx += 256) {
            const int vnl = idx / 324, rem = idx - vnl * 324;
            const int r = rem >> 2, part = rem & 3;
            const uint4 vv = *(const uint4*)(
                inT + ((size_t)(vnBase + vnl) * 81 + r) * 512 + c0 + part * 8);
            *(uint4*)(&s_in[(vnl * 81 + r) * ROWH + part * 8]) = vv;
        }
        __syncthreads();
#pragma unroll
        for (int t = 0; t < 9; ++t) {
            const int tOffA = ((t / 3) * 9 + (t % 3)) * ROWH;
            bf16x8 bw[4];
#pragma unroll
            for (int nt = 0; nt < 4; ++nt)
                bw[nt] = *(const bf16x8*)(&s_w[(t * 64 + nt * 16 + l16) * 32 + bSwz]);
            bf16x8 af[MT];
#pragma unroll
            for (int mt = 0; mt < MT; ++mt)
                af[mt] = *(const bf16x8*)(&s_in[aBase[mt] + tOffA]);
#pragma unroll
            for (int mt = 0; mt < MT; ++mt)
#pragma unroll
                for (int nt = 0; nt < 4; ++nt)
                    acc[mt][nt] = __builtin_amdgcn_mfma_f32_16x16x32_bf16(
                        af[mt], bw[nt], acc[mt][nt], 0, 0, 0);
        }
    }

    const int vn = vnBase + vn_l;
#pragma unroll
    for (int mt = 0; mt < MT; ++mt) {
#pragma unroll
        for (int r = 0; r < 4; ++r) {
            const int p = (mh * MT + mt) * 16 + q * 4 + r;
            if (p >= 49) continue;
#pragma unroll
            for (int nt = 0; nt < 4; ++nt) {
                const int oc = ocWg + nt * 16 + l16;
                const float v = acc[mt][nt][r];
                if (mode == 2) {
                    const int n = vn >> 2, quad = vn & 3;
                    const int p14 = ((quad >> 1) * 7 + p / 7) * 14 + (quad & 1) * 7 + p % 7;
                    outb[((size_t)n * 196 + p14) * 512 + oc] = (__bf16)fmaxf(v, 0.f);
                } else if (mode == 1) {
                    const size_t addr = ((size_t)vn * 49 + p) * 512 + oc;
                    const float res = v + resid[addr];
                    outf[addr] = res;
                    if (inT7out) {
                        const int sp = (p / 7 + 1) * 9 + (p % 7 + 1);
                        inT7out[((size_t)vn * 81 + sp) * 512 + oc] = (__bf16)res;
                    }
                } else {
                    const int conv = oc >> 9;
                    outb[(size_t)conv * PLANE + ((size_t)p * 64 + vn) * 512 + (oc & 511)]
                        = (__bf16)v;
                }
            }
        }
    }
}

// ---------- fused maxpool + bf16 pack (interior) + fp32 residual ----------
__global__ __launch_bounds__(256) void k_pool_prep(
    const __bf16* __restrict__ x2, __bf16* __restrict__ inT7,
    float* __restrict__ xA)
{
    const int b = blockIdx.x;                 // 64*49
    const int n = b / 49, p = b % 49;
    const int i = p / 7, j = p % 7;
    const int sp = (i + 1) * 9 + (j + 1);
#pragma unroll
    for (int k = 0; k < 2; ++k) {
        const int c = threadIdx.x + k * 256;
        float mx = -1e30f;
#pragma unroll
        for (int di = -1; di <= 1; ++di) {
            const int rr = 2 * i + di;
            if (rr < 0 || rr >= 14) continue;
#pragma unroll
            for (int dj = -1; dj <= 1; ++dj) {
                const int cc = 2 * j + dj;
                if (cc < 0 || cc >= 14) continue;
                mx = fmaxf(mx, (float)x2[((size_t)n * 196 + rr * 14 + cc) * 512 + c]);
            }
        }
        inT7[((size_t)n * 81 + sp) * 512 + c] = (__bf16)mx;
        xA[((size_t)n * 49 + p) * 512 + c] = mx;
    }
}

// ---------- fused attention: scores + softmax + virt ----------
__global__ __launch_bounds__(64) void k_attvirt(
    const __bf16* __restrict__ qT, const __bf16* __restrict__ kT,
    const __bf16* __restrict__ vT, float* __restrict__ virt)
{
    const int n = blockIdx.x, p = blockIdx.y, m = threadIdx.x;
    __shared__ float s_q[HIDC];
    {
        const uint4 v = ((const uint4*)(qT + ((size_t)p * 64 + n) * HIDC))[m];
        const unsigned* u = (const unsigned*)&v;
#pragma unroll
        for (int j = 0; j < 4; ++j) {
            s_q[m * 8 + 2 * j]     = bf2f((unsigned short)(u[j] & 0xffff));
            s_q[m * 8 + 2 * j + 1] = bf2f((unsigned short)(u[j] >> 16));
        }
    }
    __syncthreads();
    const uint4* krow = (const uint4*)(kT + ((size_t)p * 64 + m) * HIDC);
    float acc = 0.f;
    for (int i = 0; i < 64; ++i) {
        const uint4 v = krow[i];
        const unsigned* u = (const unsigned*)&v;
#pragma unroll
        for (int j = 0; j < 4; ++j) {
            acc = fmaf(s_q[i * 8 + 2 * j],     bf2f((unsigned short)(u[j] & 0xffff)), acc);
            acc = fmaf(s_q[i * 8 + 2 * j + 1], bf2f((unsigned short)(u[j] >> 16)),    acc);
        }
    }
    acc *= 0.044194173824159216f;
    float mx = acc;
#pragma unroll
    for (int off = 32; off; off >>= 1) mx = fmaxf(mx, __shfl_xor(mx, off));
    const float e = expf(acc - mx);
    float s = e;
#pragma unroll
    for (int off = 32; off; off >>= 1) s += __shfl_xor(s, off);
    __shared__ float s_a[64];
    s_a[m] = e / s;
    __syncthreads();
    const int c0 = m * 8;
    float av[8];
#pragma unroll
    for (int j = 0; j < 8; ++j) av[j] = 0.f;
    for (int mm = 0; mm < 64; ++mm) {
        const float a = s_a[mm];
        const uint4 v = *(const uint4*)(vT + ((size_t)p * 64 + mm) * HIDC + c0);
        const unsigned* u = (const unsigned*)&v;
#pragma unroll
        for (int j = 0; j < 4; ++j) {
            av[2 * j]     = fmaf(a, bf2f((unsigned short)(u[j] & 0xffff)), av[2 * j]);
            av[2 * j + 1] = fmaf(a, bf2f((unsigned short)(u[j] >> 16)),    av[2 * j + 1]);
        }
    }
    float* o = virt + ((size_t)n * 49 + p) * 512 + c0;
#pragma unroll
    for (int j = 0; j < 8; ++j) o[j] = av[j];
}

// ---------- GroupNorm(1,C) stats ----------
__global__ __launch_bounds__(1024) void k_gn_stats(
    const float* __restrict__ x, float* __restrict__ stats)
{
    const int n = blockIdx.x;
    const float* xp = x + (size_t)n * (HIDC * 49);
    float s = 0.f, sq = 0.f;
    for (int i = threadIdx.x; i < HIDC * 49; i += 1024) {
        const float v = xp[i];
        s += v; sq += v * v;
    }
#pragma unroll
    for (int off = 32; off; off >>= 1) {
        s  += __shfl_xor(s, off);
        sq += __shfl_xor(sq, off);
    }
    __shared__ float rs[16], rq[16];
    const int wv = threadIdx.x >> 6, lane = threadIdx.x & 63;
    if (lane == 0) { rs[wv] = s; rq[wv] = sq; }
    __syncthreads();
    if (threadIdx.x == 0) {
        float S = 0.f, Q = 0.f;
        for (int k = 0; k < 16; ++k) { S += rs[k]; Q += rq[k]; }
        const float mean = S / (float)(HIDC * 49);
        const float var  = Q / (float)(HIDC * 49) - mean * mean;
        stats[n * 2]     = mean;
        stats[n * 2 + 1] = rsqrtf(var + 1e-5f);
    }
}

// ---------- GN affine + relu + bf16 pack (interior only) ----------
__global__ __launch_bounds__(256) void k_prep_gn(
    const float* __restrict__ virt, const float* __restrict__ stats,
    const float* __restrict__ gamma, const float* __restrict__ beta,
    __bf16* __restrict__ inT7)
{
    const int b = blockIdx.x;                 // 64*49
    const int n = b / 49, p = b % 49;
    const int sp = (p / 7 + 1) * 9 + (p % 7 + 1);
    const float mean = stats[n * 2], inv = stats[n * 2 + 1];
#pragma unroll
    for (int k = 0; k < 2; ++k) {
        const int c = threadIdx.x + k * 256;
        const float v = virt[((size_t)n * 49 + p) * 512 + c];
        inT7[((size_t)n * 81 + sp) * 512 + c] =
            (__bf16)fmaxf((v - mean) * inv * gamma[c] + beta[c], 0.f);
    }
}

__global__ __launch_bounds__(512) void k_roi(
    const float* __restrict__ actor, const float* __restrict__ wfc1,
    float* __restrict__ roi)
{
    const int n = blockIdx.x, h = threadIdx.x;
    const float* ar = actor + n * CR;
    const float* wr = wfc1 + (size_t)h * CR;
    float acc = 0.f;
    for (int c = 0; c < CR; ++c)
        acc = fmaf(ar[c], wr[c], acc);
    roi[n * HIDC + h] = fmaxf(acc, 0.f);
}

__global__ __launch_bounds__(256) void k_gapfinal(
    const float* __restrict__ x, const float* __restrict__ roi,
    const float* __restrict__ wfc2, float* __restrict__ out)
{
    const int n = blockIdx.x;
    __shared__ float s_h[HIDC];
#pragma unroll
    for (int k = 0; k < 2; ++k) {
        const int c = threadIdx.x + k * 256;
        float s = 0.f;
        for (int p = 0; p < 49; ++p) s += x[((size_t)n * 49 + p) * 512 + c];
        s_h[c] = s * (1.f / 49.f);
    }
    __syncthreads();
    const int k = threadIdx.x;
    if (k < NCLS) {
        const float* rr = roi + n * HIDC;
        const float* wr = wfc2 + (size_t)k * (2 * HIDC);
        float acc = 0.f;
        for (int j = 0; j < HIDC; ++j) acc = fmaf(rr[j], wr[j], acc);
        for (int j = 0; j < HIDC; ++j) acc = fmaf(s_h[j], wr[HIDC + j], acc);
        out[n * NCLS + k] = acc;
    }
}

// ---------------------------------------------------------------------------
extern "C" void kernel_launch(void* const* d_in, const int* in_sizes, int n_in,
                              void* d_out, int out_size, void* d_ws, size_t ws_size,
                              hipStream_t stream) {
    const float* bg    = (const float*)d_in[0];
    const float* actor = (const float*)d_in[1];
    const float* w1    = (const float*)d_in[2];
    const float* w2    = (const float*)d_in[3];
    const float* wq    = (const float*)d_in[4];
    const float* wk    = (const float*)d_in[5];
    const float* wv    = (const float*)d_in[6];
    const float* wo    = (const float*)d_in[7];
    const float* gamma = (const float*)d_in[8];
    const float* beta  = (const float*)d_in[9];
    const float* wfc1  = (const float*)d_in[10];
    const float* wfc2  = (const float*)d_in[11];
    float* out = (float*)d_out;
    float* ws  = (float*)d_ws;

    // ---- fp32 regions ----
    float* A_T   = ws;                        // 131,072
    float* Bp    = A_T + 131072;              // 32,768
    float* xA    = Bp + 32768;                // PLANE
    float* xB    = xA + PLANE;                // PLANE
    float* stats = xB + PLANE;                // 128
    float* roi   = stats + 128;               // 32,768
    float* fend  = roi + 32768;
    // ---- bf16 regions ----
    __bf16* x2h  = (__bf16*)fend;             // 64*196*512 = 6,422,528 halves
    float*  virt = (float*)x2h;               // aliases x2h (dead after pool)
    __bf16* inT2 = x2h + 6422528;             // 256*81*512 = 10,616,832
    __bf16* qkvT = inT2;                      // aliases inT2 (dead after conv2)
    __bf16* inT7 = inT2 + 10616832;           // 64*81*512  = 2,654,208
    __bf16* wAll = inT7 + 2654208;            // 9*4608*512 = 21,233,664

    k_Apart<<<512, 256, 0, stream>>>(w1, bg, A_T);
    k_Bpart<<<64, 512, 0, stream>>>(w1, actor, Bp);
    k_prep_w<<<4608, 256, 0, stream>>>(w2, wq, wk, wv, wo, wAll);
    k_prep_in2<<<256, 256, 0, stream>>>(A_T, Bp, inT2);
    // zero inT7 once: borders stay zero across both layers
    hipMemsetAsync(inT7, 0, (size_t)64 * 81 * 512 * sizeof(__bf16), stream);

    // conv2: 256 quadrant-planes, VN2 -> grid 128 x 8 = 1024 wgs
    k_conv_mfma<2><<<dim3(128, 8), 256, 0, stream>>>(
        inT2, wAll, 0, nullptr, nullptr, x2h, nullptr, 2);
    k_pool_prep<<<64 * 49, 256, 0, stream>>>(x2h, inT7, xA);

    float* xin = xA;
    float* xout = xB;
    for (int d = 0; d < 2; ++d) {
        // fused qkv: oc 1536, VN2 -> grid 32 x 24 = 768 wgs
        k_conv_mfma<2><<<dim3(32, 24), 256, 0, stream>>>(
            inT7, wAll, 512 + d * 2048, nullptr, nullptr, qkvT, nullptr, 0);
        k_attvirt<<<dim3(64, 49), 64, 0, stream>>>(
            qkvT, qkvT + PLANE, qkvT + 2 * PLANE, virt);
        k_gn_stats<<<64, 1024, 0, stream>>>(virt, stats);
        k_prep_gn<<<64 * 49, 256, 0, stream>>>(virt, stats,
                                               gamma + d * HIDC, beta + d * HIDC, inT7);
        // wo + residual: VN1 -> grid 64 x 8 = 512 wgs; writes next layer's inT7
        k_conv_mfma<1><<<dim3(64, 8), 256, 0, stream>>>(
            inT7, wAll, 2048 + d * 2048, xin, xout, nullptr,
            d == 0 ? inT7 : nullptr, 1);
        float* t = xin; xin = xout; xout = t;
    }
    k_roi<<<64, 512, 0, stream>>>(actor, wfc1, roi);
    k_gapfinal<<<64, 256, 0, stream>>>(xin, roi, wfc2, out);
}

// Round 7
// 762.711 us; speedup vs baseline: 1.7069x; 1.0027x over previous
//
#include <hip/hip_runtime.h>
#include <math.h>

// ---------------------------------------------------------------------------
// ACARHead — R7: conv reverted to R3 config (VN4, MT4xNT4, all-9-tap s_w,
// 2 barriers/chunk — empirically best at 77us). Tail fused hard:
// 11 dispatches total. GN affine fused into wo conv staging; GN stats fused
// into attvirt (atomics, zeroed by qkv conv wg0); all prep in one kernel.
// ---------------------------------------------------------------------------

typedef __bf16 bf16x8 __attribute__((ext_vector_type(8)));
typedef float  f32x4  __attribute__((ext_vector_type(4)));

#define NROI 64
#define CR   1024
#define HIDC 512
#define NCLS 60
#define PLANE (NROI * HIDC * 49)        // 1,605,632
#define ROWH 40                          // s_in row: 32 halves + 8 pad (80 B)
#define OCALL 4608
#define TAPSTR ((size_t)OCALL * 512)
#define WL (HIDC * HIDC * 9)
#define GNCNT 25088.0f                   // 512*49

#if defined(__has_builtin)
#  if __has_builtin(__builtin_amdgcn_global_load_lds)
#    define HAVE_GLL 1
#  endif
#endif

__device__ __forceinline__ void stage16(const void* g, void* lds_base, int lane) {
#ifdef HAVE_GLL
    __builtin_amdgcn_global_load_lds(
        (const __attribute__((address_space(1))) unsigned int*)g,
        (__attribute__((address_space(3))) unsigned int*)lds_base, 16, 0, 0);
#else
    *(uint4*)((char*)lds_base + lane * 16) = *(const uint4*)g;
#endif
}

__device__ __forceinline__ float bf2f(unsigned short h) {
    union { unsigned u; float f; } x; x.u = (unsigned)h << 16; return x.f;
}

// ---------- unified prep: Apart | Bpart | weight transpose | inT7 borders --
__global__ __launch_bounds__(256) void k_prep_all(
    const float* __restrict__ w1, const float* __restrict__ bg,
    const float* __restrict__ actor,
    const float* __restrict__ w2, const float* __restrict__ wq,
    const float* __restrict__ wk, const float* __restrict__ wv,
    const float* __restrict__ wo,
    float* __restrict__ A_T, float* __restrict__ Bp,
    __bf16* __restrict__ wAll, __bf16* __restrict__ inT7)
{
    const int b = blockIdx.x, tid = threadIdx.x;
    __shared__ float s[4608];
    if (b < 512) {
        // A_T[p][o] = sum_c w1[o,c]*bg[c,p]
        const int o = b, p = tid;
        const float* wr = w1 + (size_t)o * (2 * CR);
        float acc = 0.f;
        for (int c = 0; c < CR; ++c)
            acc = fmaf(wr[c], bg[c * 256 + p], acc);
        A_T[p * HIDC + o] = acc;
    } else if (b < 576) {
        const int n = b - 512;
        const float* ar = actor + n * CR;
#pragma unroll
        for (int k = 0; k < 2; ++k) {
            const int o = tid + k * 256;
            const float* wr = w1 + (size_t)o * (2 * CR) + CR;
            float acc = 0.f;
            for (int c = 0; c < CR; ++c)
                acc = fmaf(ar[c], wr[c], acc);
            Bp[n * HIDC + o] = acc;
        }
    } else if (b < 5184) {
        // weight transpose+swizzle: row bid of wAll
        const int bid = b - 576;
        const float* src;
        if (bid < 512) src = w2 + (size_t)bid * 4608;
        else if (bid < 2048) {
            const int r = bid - 512;
            const float* bb = r < 512 ? wq : (r < 1024 ? wk : wv);
            src = bb + (size_t)(r & 511) * 4608;
        } else if (bid < 2560) src = wo + (size_t)(bid - 2048) * 4608;
        else if (bid < 4096) {
            const int r = bid - 2560;
            const float* bb = r < 512 ? wq : (r < 1024 ? wk : wv);
            src = bb + WL + (size_t)(r & 511) * 4608;
        } else src = wo + WL + (size_t)(bid - 4096) * 4608;
        for (int i = tid; i < 4608; i += 256) s[i] = src[i];
        __syncthreads();
        unsigned* dst = (unsigned*)wAll;
        const int c = tid * 2;
        const int swz = ((c >> 3) & 3) ^ ((bid >> 1) & 3);
        const size_t cidx = (size_t)(c >> 5) * 32 + swz * 8 + (c & 7);
#pragma unroll
        for (int t = 0; t < 9; ++t) {
            const unsigned short u0 = __builtin_bit_cast(unsigned short, (__bf16)s[c * 9 + t]);
            const unsigned short u1 = __builtin_bit_cast(unsigned short, (__bf16)s[(c + 1) * 9 + t]);
            dst[((size_t)t * TAPSTR + (size_t)bid * 512 + cidx) / 2] =
                ((unsigned)u1 << 16) | u0;
        }
    } else {
        // zero inT7 border rows (32 per n), 4 rows per block
        const int k = b - 5184;            // 0..511
        const int n = k >> 3;
        const int j0 = (k & 7) * 4;
#pragma unroll
        for (int i = 0; i < 4; ++i) {
            const int jj = j0 + i;
            int sp;
            if (jj < 9) sp = jj;
            else if (jj < 18) sp = 63 + jj;          // 72 + (jj-9)
            else { const int t = jj - 18; sp = (1 + (t >> 1)) * 9 + (t & 1) * 8; }
            unsigned* d = (unsigned*)(inT7 + ((size_t)n * 81 + sp) * 512);
            d[tid] = 0u;
        }
    }
}

// ---------- conv2 input: relu(A_T[p][c]+B[n][c]) -> inT2[vn][81][512] -----
__global__ __launch_bounds__(256) void k_prep_in2(
    const float* __restrict__ A_T, const float* __restrict__ B,
    __bf16* __restrict__ dst)
{
    const int vn = blockIdx.x;
    const int n = vn >> 2, quad = vn & 3;
    const float b0 = B[n * HIDC + threadIdx.x];
    const float b1 = B[n * HIDC + 256 + threadIdx.x];
    for (int sp = 0; sp < 81; ++sp) {
        const int r = sp / 9, w = sp % 9;
        const int p16 = ((quad >> 1) * 7 + r) * 16 + (quad & 1) * 7 + w;
        __bf16* d = dst + ((size_t)vn * 81 + sp) * 512;
        d[threadIdx.x]       = (__bf16)fmaxf(A_T[p16 * HIDC + threadIdx.x] + b0, 0.f);
        d[256 + threadIdx.x] = (__bf16)fmaxf(A_T[p16 * HIDC + 256 + threadIdx.x] + b1, 0.f);
    }
}

// ---------- unified MFMA conv (R3 structure) ----------
// VN4: wave=vn, MT4.  VN2: wave=(vn w&1, mh w>>1), MT2.  NT=4 (64 oc/wg).
// GNIN: input staged from fp32 virt with GroupNorm affine + relu fused.
// mode 0: qkvT bf16 [p][vn][c]; mode 1: fp32 +resid (+optional inT7 interior);
// mode 2: bf16 x2 [n][196][512] relu (conv2 quadrants).
template<int VN, bool GNIN>
__global__ __launch_bounds__(256, 2) void k_conv_mfma(
    const __bf16* __restrict__ inT,    // !GNIN: [vn][81][512]
    const float* __restrict__ vin,     // GNIN: virt fp32 [vn][49][512]
    const float* __restrict__ statsRaw,
    const float* __restrict__ gamma, const float* __restrict__ beta,
    const __bf16* __restrict__ wAll, int ocBaseGl,
    const float* __restrict__ resid, float* __restrict__ outf,
    __bf16* __restrict__ outb, __bf16* __restrict__ inT7out,
    float* __restrict__ zeroStats, int mode)
{
    constexpr int MT = (VN == 4) ? 4 : 2;
    const int tid = threadIdx.x;
    const int w = tid >> 6, lane = tid & 63;
    const int q = lane >> 4, l16 = lane & 15;
    const int vn_l = (VN == 4) ? w : (w & 1);
    const int mh   = (VN == 4) ? 0 : (w >> 1);
    const int vnBase = blockIdx.x * VN;
    const int ocWg = blockIdx.y * 64;

    if (zeroStats && blockIdx.x == 0 && blockIdx.y == 0 && tid < 128)
        zeroStats[tid] = 0.f;

    __shared__ __align__(16) __bf16 s_w[9 * 64 * 32];      // 36,864 B
    __shared__ __align__(16) __bf16 s_in[VN * 81 * ROWH];
    __shared__ float s_mi[VN][2];

    if (GNIN && tid < VN) {
        const float S = statsRaw[(vnBase + tid) * 2];
        const float Q = statsRaw[(vnBase + tid) * 2 + 1];
        const float mean = S / GNCNT;
        const float var  = Q / GNCNT - mean * mean;
        s_mi[tid][0] = mean;
        s_mi[tid][1] = rsqrtf(var + 1e-5f);
    }

    const int bSwz = (q ^ ((l16 >> 1) & 3)) << 3;
    int aBase[MT];
#pragma unroll
    for (int mt = 0; mt < MT; ++mt) {
        int p = (mh * MT + mt) * 16 + l16;
        p = p > 48 ? 48 : p;
        aBase[mt] = (vn_l * 81 + (p / 7) * 9 + (p % 7)) * ROWH + q * 8;
    }

    f32x4 acc[MT][4];
#pragma unroll
    for (int a = 0; a < MT; ++a)
#pragma unroll
        for (int b = 0; b < 4; ++b) acc[a][b] = (f32x4){0.f, 0.f, 0.f, 0.f};

    for (int ch = 0; ch < 16; ++ch) {
        const int c0 = ch * 32;
        __syncthreads();
        // --- weights: all 9 taps, async global->LDS (9 insts/wave) ---
#pragma unroll
        for (int i = 0; i < 9; ++i) {
            const int s0 = (w * 9 + i) * 64;
            const int s = s0 + lane;
            const int t = s >> 8;
            const int rem = s & 255;
            const int row = rem >> 2, part = rem & 3;
            const __bf16* g = wAll + (size_t)t * TAPSTR
                + (size_t)(ocBaseGl + ocWg + row) * 512 + c0 + part * 8;
            stage16(g, (char*)s_w + (size_t)s0 * 16, lane);
        }
        // --- input plane(s) ---
        for (int idx = tid; idx < VN * 324; idx += 256) {
            const int vnl = idx / 324, rem = idx - vnl * 324;
            const int r = rem >> 2, part = rem & 3;
            if (GNIN) {
                const int rr = r / 9, cc = r % 9;
                bf16x8 val;
                if (rr >= 1 && rr <= 7 && cc >= 1 && cc <= 7) {
                    const int p = (rr - 1) * 7 + (cc - 1);
                    const float* src = vin +
                        ((size_t)(vnBase + vnl) * 49 + p) * 512 + c0 + part * 8;
                    const float4 g0 = *(const float4*)(gamma + c0 + part * 8);
                    const float4 g1 = *(const float4*)(gamma + c0 + part * 8 + 4);
                    const float4 b0 = *(const float4*)(beta + c0 + part * 8);
                    const float4 b1 = *(const float4*)(beta + c0 + part * 8 + 4);
                    const float m = s_mi[vnl][0], iv = s_mi[vnl][1];
                    const float* gg = (const float*)&g0;
                    const float* bb = (const float*)&b0;
#pragma unroll
                    for (int j = 0; j < 4; ++j)
                        val[j] = (__bf16)fmaxf((src[j] - m) * iv * gg[j] + bb[j], 0.f);
                    const float* gh = (const float*)&g1;
                    const float* bh = (const float*)&b1;
#pragma unroll
                    for (int j = 0; j < 4; ++j)
                        val[4 + j] = (__bf16)fmaxf((src[4 + j] - m) * iv * gh[j] + bh[j], 0.f);
                } else {
#pragma unroll
                    for (int j = 0; j < 8; ++j) val[j] = (__bf16)0.f;
                }
                *(bf16x8*)(&s_in[(vnl * 81 + r) * ROWH + part * 8]) = val;
            } else {
                const uint4 vv = *(const uint4*)(
                    inT + ((size_t)(vnBase + vnl) * 81 + r) * 512 + c0 + part * 8);
                *(uint4*)(&s_in[(vnl * 81 + r) * ROWH + part * 8]) = vv;
            }
        }
        __syncthreads();
#pragma unroll
        for (int t = 0; t < 9; ++t) {
            const int tOffA = ((t / 3) * 9 + (t % 3)) * ROWH;
            bf16x8 bw[4];
#pragma unroll
            for (int nt = 0; nt < 4; ++nt)
                bw[nt] = *(const bf16x8*)(&s_w[(t * 64 + nt * 16 + l16) * 32 + bSwz]);
            bf16x8 af[MT];
#pragma unroll
            for (int mt = 0; mt < MT; ++mt)
                af[mt] = *(const bf16x8*)(&s_in[aBase[mt] + tOffA]);
#pragma unroll
            for (int mt = 0; mt < MT; ++mt)
#pragma unroll
                for (int nt = 0; nt < 4; ++nt)
                    acc[mt][nt] = __builtin_amdgcn_mfma_f32_16x16x32_bf16(
                        af[mt], bw[nt], acc[mt][nt], 0, 0, 0);
        }
    }

    const int vn = vnBase + vn_l;
#pragma unroll
    for (int mt = 0; mt < MT; ++mt) {
#pragma unroll
        for (int r = 0; r < 4; ++r) {
            const int p = (mh * MT + mt) * 16 + q * 4 + r;
            if (p >= 49) continue;
#pragma unroll
            for (int nt = 0; nt < 4; ++nt) {
                const int oc = ocWg + nt * 16 + l16;
                const float v = acc[mt][nt][r];
                if (mode == 2) {
                    const int n = vn >> 2, quad = vn & 3;
                    const int p14 = ((quad >> 1) * 7 + p / 7) * 14 + (quad & 1) * 7 + p % 7;
                    outb[((size_t)n * 196 + p14) * 512 + oc] = (__bf16)fmaxf(v, 0.f);
                } else if (mode == 1) {
                    const size_t addr = ((size_t)vn * 49 + p) * 512 + oc;
                    const float res = v + resid[addr];
                    outf[addr] = res;
                    if (inT7out) {
                        const int sp = (p / 7 + 1) * 9 + (p % 7 + 1);
                        inT7out[((size_t)vn * 81 + sp) * 512 + oc] = (__bf16)res;
                    }
                } else {
                    const int conv = oc >> 9;
                    outb[(size_t)conv * PLANE + ((size_t)p * 64 + vn) * 512 + (oc & 511)]
                        = (__bf16)v;
                }
            }
        }
    }
}

// ---------- fused maxpool + bf16 pack (interior) + fp32 residual ----------
__global__ __launch_bounds__(256) void k_pool_prep(
    const __bf16* __restrict__ x2, __bf16* __restrict__ inT7,
    float* __restrict__ xA)
{
    const int b = blockIdx.x;                 // 64*49
    const int n = b / 49, p = b % 49;
    const int i = p / 7, j = p % 7;
    const int sp = (i + 1) * 9 + (j + 1);
#pragma unroll
    for (int k = 0; k < 2; ++k) {
        const int c = threadIdx.x + k * 256;
        float mx = -1e30f;
#pragma unroll
        for (int di = -1; di <= 1; ++di) {
            const int rr = 2 * i + di;
            if (rr < 0 || rr >= 14) continue;
#pragma unroll
            for (int dj = -1; dj <= 1; ++dj) {
                const int cc = 2 * j + dj;
                if (cc < 0 || cc >= 14) continue;
                mx = fmaxf(mx, (float)x2[((size_t)n * 196 + rr * 14 + cc) * 512 + c]);
            }
        }
        inT7[((size_t)n * 81 + sp) * 512 + c] = (__bf16)mx;
        xA[((size_t)n * 49 + p) * 512 + c] = mx;
    }
}

// ---------- fused attention + GN partial stats ----------
// block 256 = 4 waves; wave w handles n = blockIdx.x*4+w at p = blockIdx.y.
__global__ __launch_bounds__(256) void k_attvirt(
    const __bf16* __restrict__ qT, const __bf16* __restrict__ kT,
    const __bf16* __restrict__ vT, float* __restrict__ virt,
    float* __restrict__ statsRaw)
{
    const int p = blockIdx.y;
    const int w = threadIdx.x >> 6, m = threadIdx.x & 63;
    const int n = blockIdx.x * 4 + w;
    __shared__ float s_q[4][HIDC];
    __shared__ float s_a[4][64];
    {
        const uint4 v = ((const uint4*)(qT + ((size_t)p * 64 + n) * HIDC))[m];
        const unsigned* u = (const unsigned*)&v;
#pragma unroll
        for (int j = 0; j < 4; ++j) {
            s_q[w][m * 8 + 2 * j]     = bf2f((unsigned short)(u[j] & 0xffff));
            s_q[w][m * 8 + 2 * j + 1] = bf2f((unsigned short)(u[j] >> 16));
        }
    }
    __syncthreads();
    const uint4* krow = (const uint4*)(kT + ((size_t)p * 64 + m) * HIDC);
    float acc = 0.f;
    for (int i = 0; i < 64; ++i) {
        const uint4 v = krow[i];
        const unsigned* u = (const unsigned*)&v;
#pragma unroll
        for (int j = 0; j < 4; ++j) {
            acc = fmaf(s_q[w][i * 8 + 2 * j],     bf2f((unsigned short)(u[j] & 0xffff)), acc);
            acc = fmaf(s_q[w][i * 8 + 2 * j + 1], bf2f((unsigned short)(u[j] >> 16)),    acc);
        }
    }
    acc *= 0.044194173824159216f;
    float mx = acc;
#pragma unroll
    for (int off = 32; off; off >>= 1) mx = fmaxf(mx, __shfl_xor(mx, off));
    const float e = expf(acc - mx);
    float s = e;
#pragma unroll
    for (int off = 32; off; off >>= 1) s += __shfl_xor(s, off);
    s_a[w][m] = e / s;
    __syncthreads();
    const int c0 = m * 8;
    float av[8];
#pragma unroll
    for (int j = 0; j < 8; ++j) av[j] = 0.f;
    for (int mm = 0; mm < 64; ++mm) {
        const float a = s_a[w][mm];
        const uint4 v = *(const uint4*)(vT + ((size_t)p * 64 + mm) * HIDC + c0);
        const unsigned* u = (const unsigned*)&v;
#pragma unroll
        for (int j = 0; j < 4; ++j) {
            av[2 * j]     = fmaf(a, bf2f((unsigned short)(u[j] & 0xffff)), av[2 * j]);
            av[2 * j + 1] = fmaf(a, bf2f((unsigned short)(u[j] >> 16)),    av[2 * j + 1]);
        }
    }
    float* o = virt + ((size_t)n * 49 + p) * 512 + c0;
    float ps = 0.f, pq = 0.f;
#pragma unroll
    for (int j = 0; j < 8; ++j) {
        o[j] = av[j];
        ps += av[j];
        pq = fmaf(av[j], av[j], pq);
    }
#pragma unroll
    for (int off = 32; off; off >>= 1) {
        ps += __shfl_xor(ps, off);
        pq += __shfl_xor(pq, off);
    }
    if (m == 0) {
        atomicAdd(statsRaw + n * 2, ps);
        atomicAdd(statsRaw + n * 2 + 1, pq);
    }
}

// ---------- fused roi + gap + final fc ----------
__global__ __launch_bounds__(256) void k_gapfinal(
    const float* __restrict__ x, const float* __restrict__ actor,
    const float* __restrict__ wfc1, const float* __restrict__ wfc2,
    float* __restrict__ out)
{
    const int n = blockIdx.x;
    __shared__ float s_h[HIDC], s_r[HIDC];
    const float4* a4 = (const float4*)(actor + (size_t)n * CR);
#pragma unroll
    for (int k = 0; k < 2; ++k) {
        const int h = threadIdx.x + k * 256;
        // roi
        const float4* w4 = (const float4*)(wfc1 + (size_t)h * CR);
        float acc = 0.f;
        for (int i = 0; i < CR / 4; ++i) {
            const float4 a = a4[i], b = w4[i];
            acc = fmaf(a.x, b.x, acc); acc = fmaf(a.y, b.y, acc);
            acc = fmaf(a.z, b.z, acc); acc = fmaf(a.w, b.w, acc);
        }
        s_r[h] = fmaxf(acc, 0.f);
        // gap
        float s = 0.f;
        for (int p = 0; p < 49; ++p) s += x[((size_t)n * 49 + p) * 512 + h];
        s_h[h] = s * (1.f / 49.f);
    }
    __syncthreads();
    const int k = threadIdx.x;
    if (k < NCLS) {
        const float* wr = wfc2 + (size_t)k * (2 * HIDC);
        float acc = 0.f;
        for (int j = 0; j < HIDC; ++j) acc = fmaf(s_r[j], wr[j], acc);
        for (int j = 0; j < HIDC; ++j) acc = fmaf(s_h[j], wr[HIDC + j], acc);
        out[n * NCLS + k] = acc;
    }
}

// ---------------------------------------------------------------------------
extern "C" void kernel_launch(void* const* d_in, const int* in_sizes, int n_in,
                              void* d_out, int out_size, void* d_ws, size_t ws_size,
                              hipStream_t stream) {
    const float* bg    = (const float*)d_in[0];
    const float* actor = (const float*)d_in[1];
    const float* w1    = (const float*)d_in[2];
    const float* w2    = (const float*)d_in[3];
    const float* wq    = (const float*)d_in[4];
    const float* wk    = (const float*)d_in[5];
    const float* wv    = (const float*)d_in[6];
    const float* wo    = (const float*)d_in[7];
    const float* gamma = (const float*)d_in[8];
    const float* beta  = (const float*)d_in[9];
    const float* wfc1  = (const float*)d_in[10];
    const float* wfc2  = (const float*)d_in[11];
    float* out = (float*)d_out;
    float* ws  = (float*)d_ws;

    // ---- fp32 regions ----
    float* A_T   = ws;                        // 131,072
    float* Bp    = A_T + 131072;              // 32,768
    float* xA    = Bp + 32768;                // PLANE
    float* xB    = xA + PLANE;                // PLANE
    float* stats = xB + PLANE;                // 128
    float* fend  = stats + 128;
    // ---- bf16 regions ----
    __bf16* x2h  = (__bf16*)fend;             // 64*196*512 = 6,422,528 halves
    float*  virt = (float*)x2h;               // aliases x2h (dead after pool)
    __bf16* inT2 = x2h + 6422528;             // 256*81*512 = 10,616,832
    __bf16* qkvT = inT2;                      // aliases inT2 (dead after conv2)
    __bf16* inT7 = inT2 + 10616832;           // 64*81*512  = 2,654,208
    __bf16* wAll = inT7 + 2654208;            // 9*4608*512 = 21,233,664

    // 1: all preprocessing in one dispatch
    k_prep_all<<<5696, 256, 0, stream>>>(
        w1, bg, actor, w2, wq, wk, wv, wo, A_T, Bp, wAll, inT7);
    // 2: conv2 input planes
    k_prep_in2<<<256, 256, 0, stream>>>(A_T, Bp, inT2);
    // 3: conv2 (VN4, 512 wgs)
    k_conv_mfma<4, false><<<dim3(64, 8), 256, 0, stream>>>(
        inT2, nullptr, nullptr, nullptr, nullptr, wAll, 0,
        nullptr, nullptr, x2h, nullptr, nullptr, 2);
    // 4: pool + pack + residual
    k_pool_prep<<<64 * 49, 256, 0, stream>>>(x2h, inT7, xA);

    float* xin = xA;
    float* xout = xB;
    for (int d = 0; d < 2; ++d) {
        // 5/8: fused qkv (VN4, 384 wgs), zeroes stats for this layer
        k_conv_mfma<4, false><<<dim3(16, 24), 256, 0, stream>>>(
            inT7, nullptr, nullptr, nullptr, nullptr, wAll, 512 + d * 2048,
            nullptr, nullptr, qkvT, nullptr, stats, 0);
        // 6/9: attention + GN partial stats
        k_attvirt<<<dim3(16, 49), 256, 0, stream>>>(
            qkvT, qkvT + PLANE, qkvT + 2 * PLANE, virt, stats);
        // 7/10: wo conv with fused GN-affine+relu staging (VN2, 256 wgs)
        k_conv_mfma<2, true><<<dim3(32, 8), 256, 0, stream>>>(
            nullptr, virt, stats, gamma + d * HIDC, beta + d * HIDC,
            wAll, 2048 + d * 2048, xin, xout, nullptr,
            d == 0 ? inT7 : nullptr, nullptr, 1);
        float* t = xin; xin = xout; xout = t;
    }
    // 11: roi + gap + final fc
    k_gapfinal<<<64, 256, 0, stream>>>(xin, actor, wfc1, wfc2, out);
}

// Round 8
// 726.729 us; speedup vs baseline: 1.7914x; 1.0495x over previous
//
#include <hip/hip_runtime.h>
#include <math.h>

// ---------------------------------------------------------------------------
// ACARHead — R8: R7 + prep overhaul. k_prep_all's A-part (serial 1024-FMA
// chain, ~80us straggler) replaced by a tiny MFMA GEMM (k_ab) computing both
// A_T = w1q@bg and Bp = actor@w1k. k_misc does weight transpose (float4
// reads) + inT7 borders + bg transpose to bf16. Convs unchanged (R3 config).
// ---------------------------------------------------------------------------

typedef __bf16 bf16x8 __attribute__((ext_vector_type(8)));
typedef float  f32x4  __attribute__((ext_vector_type(4)));

#define NROI 64
#define CR   1024
#define HIDC 512
#define NCLS 60
#define PLANE (NROI * HIDC * 49)        // 1,605,632
#define ROWH 40                          // padded LDS row: 32 halves + 8 pad
#define OCALL 4608
#define TAPSTR ((size_t)OCALL * 512)
#define WL (HIDC * HIDC * 9)
#define GNCNT 25088.0f                   // 512*49

#if defined(__has_builtin)
#  if __has_builtin(__builtin_amdgcn_global_load_lds)
#    define HAVE_GLL 1
#  endif
#endif

__device__ __forceinline__ void stage16(const void* g, void* lds_base, int lane) {
#ifdef HAVE_GLL
    __builtin_amdgcn_global_load_lds(
        (const __attribute__((address_space(1))) unsigned int*)g,
        (__attribute__((address_space(3))) unsigned int*)lds_base, 16, 0, 0);
#else
    *(uint4*)((char*)lds_base + lane * 16) = *(const uint4*)g;
#endif
}

__device__ __forceinline__ float bf2f(unsigned short h) {
    union { unsigned u; float f; } x; x.u = (unsigned)h << 16; return x.f;
}

// ---------- misc prep: weight transpose | inT7 borders | bg -> bgT bf16 ----
// blocks [0,4608): wAll row; [4608,5120): border zero; [5120,5248): bgT.
__global__ __launch_bounds__(256) void k_misc(
    const float* __restrict__ w2, const float* __restrict__ wq,
    const float* __restrict__ wk, const float* __restrict__ wv,
    const float* __restrict__ wo, const float* __restrict__ bg,
    __bf16* __restrict__ wAll, __bf16* __restrict__ inT7,
    __bf16* __restrict__ bgT)
{
    const int b = blockIdx.x, tid = threadIdx.x;
    if (b < 4608) {
        const int bid = b;
        const float* src;
        if (bid < 512) src = w2 + (size_t)bid * 4608;
        else if (bid < 2048) {
            const int r = bid - 512;
            const float* bb = r < 512 ? wq : (r < 1024 ? wk : wv);
            src = bb + (size_t)(r & 511) * 4608;
        } else if (bid < 2560) src = wo + (size_t)(bid - 2048) * 4608;
        else if (bid < 4096) {
            const int r = bid - 2560;
            const float* bb = r < 512 ? wq : (r < 1024 ? wk : wv);
            src = bb + WL + (size_t)(r & 511) * 4608;
        } else src = wo + WL + (size_t)(bid - 4096) * 4608;
        __shared__ float s[4608];
        const float4* s4 = (const float4*)src;
        for (int i = tid; i < 1152; i += 256) ((float4*)s)[i] = s4[i];
        __syncthreads();
        unsigned* dst = (unsigned*)wAll;
        const int c = tid * 2;
        const int swz = ((c >> 3) & 3) ^ ((bid >> 1) & 3);
        const size_t cidx = (size_t)(c >> 5) * 32 + swz * 8 + (c & 7);
#pragma unroll
        for (int t = 0; t < 9; ++t) {
            const unsigned short u0 = __builtin_bit_cast(unsigned short, (__bf16)s[c * 9 + t]);
            const unsigned short u1 = __builtin_bit_cast(unsigned short, (__bf16)s[(c + 1) * 9 + t]);
            dst[((size_t)t * TAPSTR + (size_t)bid * 512 + cidx) / 2] =
                ((unsigned)u1 << 16) | u0;
        }
    } else if (b < 5120) {
        const int k = b - 4608;            // 0..511
        const int n = k >> 3;
        const int j0 = (k & 7) * 4;
#pragma unroll
        for (int i = 0; i < 4; ++i) {
            const int jj = j0 + i;
            int sp;
            if (jj < 9) sp = jj;
            else if (jj < 18) sp = 63 + jj;
            else { const int t = jj - 18; sp = (1 + (t >> 1)) * 9 + (t & 1) * 8; }
            unsigned* d = (unsigned*)(inT7 + ((size_t)n * 81 + sp) * 512);
            d[tid] = 0u;
        }
    } else {
        // bgT[p][c] bf16 from bg[c][p]; block handles 8 c for all 256 p
        const int cb = (b - 5120) * 8;
        const int p = tid;
        bf16x8 v;
#pragma unroll
        for (int j = 0; j < 8; ++j)
            v[j] = (__bf16)bg[(size_t)(cb + j) * 256 + p];
        *(bf16x8*)(bgT + (size_t)p * 1024 + cb) = v;
    }
}

// ---------- tiny MFMA GEMM: A_T[p][o] and Bp[n][o] ----------
// grid (5, 8): bx<4 -> A-part (M=p, A-src bgT bf16, B-src w1 cols [0,1024));
// bx==4 -> B-part (M=n, A-src actor fp32 inline-cvt, w1 cols [1024,2048)).
__global__ __launch_bounds__(256, 2) void k_ab(
    const __bf16* __restrict__ bgT, const float* __restrict__ actor,
    const float* __restrict__ w1,
    float* __restrict__ A_T, float* __restrict__ Bp)
{
    const int bx = blockIdx.x, by = blockIdx.y;
    const bool isA = bx < 4;
    const int ocWg = by * 64;
    const int tid = threadIdx.x;
    const int w = tid >> 6, lane = tid & 63;
    const int q = lane >> 4, l16 = lane & 15;

    __shared__ __align__(16) __bf16 s_a[64 * ROWH];
    __shared__ __align__(16) __bf16 s_b[64 * ROWH];

    f32x4 acc[4];
#pragma unroll
    for (int nt = 0; nt < 4; ++nt) acc[nt] = (f32x4){0.f, 0.f, 0.f, 0.f};

    const int row = tid >> 2, part = tid & 3;
    for (int ch = 0; ch < 32; ++ch) {
        const int c0 = ch * 32;
        __syncthreads();
        if (isA) {
            const uint4 vv = *(const uint4*)(
                bgT + (size_t)(bx * 64 + row) * 1024 + c0 + part * 8);
            *(uint4*)(&s_a[row * ROWH + part * 8]) = vv;
        } else {
            const float* src = actor + (size_t)row * CR + c0 + part * 8;
            bf16x8 val;
#pragma unroll
            for (int j = 0; j < 8; ++j) val[j] = (__bf16)src[j];
            *(bf16x8*)(&s_a[row * ROWH + part * 8]) = val;
        }
        {
            const float* srcb = w1 + (size_t)(ocWg + row) * (2 * CR)
                              + (isA ? 0 : CR) + c0 + part * 8;
            bf16x8 vb;
#pragma unroll
            for (int j = 0; j < 8; ++j) vb[j] = (__bf16)srcb[j];
            *(bf16x8*)(&s_b[row * ROWH + part * 8]) = vb;
        }
        __syncthreads();
        const bf16x8 af = *(const bf16x8*)(&s_a[(w * 16 + l16) * ROWH + q * 8]);
#pragma unroll
        for (int nt = 0; nt < 4; ++nt) {
            const bf16x8 bw = *(const bf16x8*)(&s_b[(nt * 16 + l16) * ROWH + q * 8]);
            acc[nt] = __builtin_amdgcn_mfma_f32_16x16x32_bf16(af, bw, acc[nt], 0, 0, 0);
        }
    }
#pragma unroll
    for (int r = 0; r < 4; ++r) {
#pragma unroll
        for (int nt = 0; nt < 4; ++nt) {
            const int mrow = w * 16 + q * 4 + r;
            const int oc = ocWg + nt * 16 + l16;
            if (isA) A_T[(size_t)(bx * 64 + mrow) * 512 + oc] = acc[nt][r];
            else     Bp[(size_t)mrow * 512 + oc] = acc[nt][r];
        }
    }
}

// ---------- conv2 input: relu(A_T[p][c]+B[n][c]) -> inT2[vn][81][512] -----
__global__ __launch_bounds__(256) void k_prep_in2(
    const float* __restrict__ A_T, const float* __restrict__ B,
    __bf16* __restrict__ dst)
{
    const int vn = blockIdx.x;
    const int n = vn >> 2, quad = vn & 3;
    const int sp0 = blockIdx.y * 27;
    const float b0 = B[n * HIDC + threadIdx.x];
    const float b1 = B[n * HIDC + 256 + threadIdx.x];
    for (int sp = sp0; sp < sp0 + 27; ++sp) {
        const int r = sp / 9, w = sp % 9;
        const int p16 = ((quad >> 1) * 7 + r) * 16 + (quad & 1) * 7 + w;
        __bf16* d = dst + ((size_t)vn * 81 + sp) * 512;
        d[threadIdx.x]       = (__bf16)fmaxf(A_T[p16 * HIDC + threadIdx.x] + b0, 0.f);
        d[256 + threadIdx.x] = (__bf16)fmaxf(A_T[p16 * HIDC + 256 + threadIdx.x] + b1, 0.f);
    }
}

// ---------- unified MFMA conv (R3 structure, unchanged from R7) ----------
template<int VN, bool GNIN>
__global__ __launch_bounds__(256, 2) void k_conv_mfma(
    const __bf16* __restrict__ inT,
    const float* __restrict__ vin,
    const float* __restrict__ statsRaw,
    const float* __restrict__ gamma, const float* __restrict__ beta,
    const __bf16* __restrict__ wAll, int ocBaseGl,
    const float* __restrict__ resid, float* __restrict__ outf,
    __bf16* __restrict__ outb, __bf16* __restrict__ inT7out,
    float* __restrict__ zeroStats, int mode)
{
    constexpr int MT = (VN == 4) ? 4 : 2;
    const int tid = threadIdx.x;
    const int w = tid >> 6, lane = tid & 63;
    const int q = lane >> 4, l16 = lane & 15;
    const int vn_l = (VN == 4) ? w : (w & 1);
    const int mh   = (VN == 4) ? 0 : (w >> 1);
    const int vnBase = blockIdx.x * VN;
    const int ocWg = blockIdx.y * 64;

    if (zeroStats && blockIdx.x == 0 && blockIdx.y == 0 && tid < 128)
        zeroStats[tid] = 0.f;

    __shared__ __align__(16) __bf16 s_w[9 * 64 * 32];
    __shared__ __align__(16) __bf16 s_in[VN * 81 * ROWH];
    __shared__ float s_mi[VN][2];

    if (GNIN && tid < VN) {
        const float S = statsRaw[(vnBase + tid) * 2];
        const float Q = statsRaw[(vnBase + tid) * 2 + 1];
        const float mean = S / GNCNT;
        const float var  = Q / GNCNT - mean * mean;
        s_mi[tid][0] = mean;
        s_mi[tid][1] = rsqrtf(var + 1e-5f);
    }

    const int bSwz = (q ^ ((l16 >> 1) & 3)) << 3;
    int aBase[MT];
#pragma unroll
    for (int mt = 0; mt < MT; ++mt) {
        int p = (mh * MT + mt) * 16 + l16;
        p = p > 48 ? 48 : p;
        aBase[mt] = (vn_l * 81 + (p / 7) * 9 + (p % 7)) * ROWH + q * 8;
    }

    f32x4 acc[MT][4];
#pragma unroll
    for (int a = 0; a < MT; ++a)
#pragma unroll
        for (int b = 0; b < 4; ++b) acc[a][b] = (f32x4){0.f, 0.f, 0.f, 0.f};

    for (int ch = 0; ch < 16; ++ch) {
        const int c0 = ch * 32;
        __syncthreads();
#pragma unroll
        for (int i = 0; i < 9; ++i) {
            const int s0 = (w * 9 + i) * 64;
            const int s = s0 + lane;
            const int t = s >> 8;
            const int rem = s & 255;
            const int row = rem >> 2, part = rem & 3;
            const __bf16* g = wAll + (size_t)t * TAPSTR
                + (size_t)(ocBaseGl + ocWg + row) * 512 + c0 + part * 8;
            stage16(g, (char*)s_w + (size_t)s0 * 16, lane);
        }
        for (int idx = tid; idx < VN * 324; idx += 256) {
            const int vnl = idx / 324, rem = idx - vnl * 324;
            const int r = rem >> 2, part = rem & 3;
            if (GNIN) {
                const int rr = r / 9, cc = r % 9;
                bf16x8 val;
                if (rr >= 1 && rr <= 7 && cc >= 1 && cc <= 7) {
                    const int p = (rr - 1) * 7 + (cc - 1);
                    const float* src = vin +
                        ((size_t)(vnBase + vnl) * 49 + p) * 512 + c0 + part * 8;
                    const float4 g0 = *(const float4*)(gamma + c0 + part * 8);
                    const float4 g1 = *(const float4*)(gamma + c0 + part * 8 + 4);
                    const float4 b0 = *(const float4*)(beta + c0 + part * 8);
                    const float4 b1 = *(const float4*)(beta + c0 + part * 8 + 4);
                    const float m = s_mi[vnl][0], iv = s_mi[vnl][1];
                    const float* gg = (const float*)&g0;
                    const float* bb = (const float*)&b0;
#pragma unroll
                    for (int j = 0; j < 4; ++j)
                        val[j] = (__bf16)fmaxf((src[j] - m) * iv * gg[j] + bb[j], 0.f);
                    const float* gh = (const float*)&g1;
                    const float* bh = (const float*)&b1;
#pragma unroll
                    for (int j = 0; j < 4; ++j)
                        val[4 + j] = (__bf16)fmaxf((src[4 + j] - m) * iv * gh[j] + bh[j], 0.f);
                } else {
#pragma unroll
                    for (int j = 0; j < 8; ++j) val[j] = (__bf16)0.f;
                }
                *(bf16x8*)(&s_in[(vnl * 81 + r) * ROWH + part * 8]) = val;
            } else {
                const uint4 vv = *(const uint4*)(
                    inT + ((size_t)(vnBase + vnl) * 81 + r) * 512 + c0 + part * 8);
                *(uint4*)(&s_in[(vnl * 81 + r) * ROWH + part * 8]) = vv;
            }
        }
        __syncthreads();
#pragma unroll
        for (int t = 0; t < 9; ++t) {
            const int tOffA = ((t / 3) * 9 + (t % 3)) * ROWH;
            bf16x8 bw[4];
#pragma unroll
            for (int nt = 0; nt < 4; ++nt)
                bw[nt] = *(const bf16x8*)(&s_w[(t * 64 + nt * 16 + l16) * 32 + bSwz]);
            bf16x8 af[MT];
#pragma unroll
            for (int mt = 0; mt < MT; ++mt)
                af[mt] = *(const bf16x8*)(&s_in[aBase[mt] + tOffA]);
#pragma unroll
            for (int mt = 0; mt < MT; ++mt)
#pragma unroll
                for (int nt = 0; nt < 4; ++nt)
                    acc[mt][nt] = __builtin_amdgcn_mfma_f32_16x16x32_bf16(
                        af[mt], bw[nt], acc[mt][nt], 0, 0, 0);
        }
    }

    const int vn = vnBase + vn_l;
#pragma unroll
    for (int mt = 0; mt < MT; ++mt) {
#pragma unroll
        for (int r = 0; r < 4; ++r) {
            const int p = (mh * MT + mt) * 16 + q * 4 + r;
            if (p >= 49) continue;
#pragma unroll
            for (int nt = 0; nt < 4; ++nt) {
                const int oc = ocWg + nt * 16 + l16;
                const float v = acc[mt][nt][r];
                if (mode == 2) {
                    const int n = vn >> 2, quad = vn & 3;
                    const int p14 = ((quad >> 1) * 7 + p / 7) * 14 + (quad & 1) * 7 + p % 7;
                    outb[((size_t)n * 196 + p14) * 512 + oc] = (__bf16)fmaxf(v, 0.f);
                } else if (mode == 1) {
                    const size_t addr = ((size_t)vn * 49 + p) * 512 + oc;
                    const float res = v + resid[addr];
                    outf[addr] = res;
                    if (inT7out) {
                        const int sp = (p / 7 + 1) * 9 + (p % 7 + 1);
                        inT7out[((size_t)vn * 81 + sp) * 512 + oc] = (__bf16)res;
                    }
                } else {
                    const int conv = oc >> 9;
                    outb[(size_t)conv * PLANE + ((size_t)p * 64 + vn) * 512 + (oc & 511)]
                        = (__bf16)v;
                }
            }
        }
    }
}

// ---------- fused maxpool + bf16 pack (interior) + fp32 residual ----------
__global__ __launch_bounds__(256) void k_pool_prep(
    const __bf16* __restrict__ x2, __bf16* __restrict__ inT7,
    float* __restrict__ xA)
{
    const int b = blockIdx.x;
    const int n = b / 49, p = b % 49;
    const int i = p / 7, j = p % 7;
    const int sp = (i + 1) * 9 + (j + 1);
#pragma unroll
    for (int k = 0; k < 2; ++k) {
        const int c = threadIdx.x + k * 256;
        float mx = -1e30f;
#pragma unroll
        for (int di = -1; di <= 1; ++di) {
            const int rr = 2 * i + di;
            if (rr < 0 || rr >= 14) continue;
#pragma unroll
            for (int dj = -1; dj <= 1; ++dj) {
                const int cc = 2 * j + dj;
                if (cc < 0 || cc >= 14) continue;
                mx = fmaxf(mx, (float)x2[((size_t)n * 196 + rr * 14 + cc) * 512 + c]);
            }
        }
        inT7[((size_t)n * 81 + sp) * 512 + c] = (__bf16)mx;
        xA[((size_t)n * 49 + p) * 512 + c] = mx;
    }
}

// ---------- fused attention + GN partial stats ----------
__global__ __launch_bounds__(256) void k_attvirt(
    const __bf16* __restrict__ qT, const __bf16* __restrict__ kT,
    const __bf16* __restrict__ vT, float* __restrict__ virt,
    float* __restrict__ statsRaw)
{
    const int p = blockIdx.y;
    const int w = threadIdx.x >> 6, m = threadIdx.x & 63;
    const int n = blockIdx.x * 4 + w;
    __shared__ float s_q[4][HIDC];
    __shared__ float s_a[4][64];
    {
        const uint4 v = ((const uint4*)(qT + ((size_t)p * 64 + n) * HIDC))[m];
        const unsigned* u = (const unsigned*)&v;
#pragma unroll
        for (int j = 0; j < 4; ++j) {
            s_q[w][m * 8 + 2 * j]     = bf2f((unsigned short)(u[j] & 0xffff));
            s_q[w][m * 8 + 2 * j + 1] = bf2f((unsigned short)(u[j] >> 16));
        }
    }
    __syncthreads();
    const uint4* krow = (const uint4*)(kT + ((size_t)p * 64 + m) * HIDC);
    float acc0 = 0.f, acc1 = 0.f;
    for (int i = 0; i < 64; ++i) {
        const uint4 v = krow[i];
        const unsigned* u = (const unsigned*)&v;
#pragma unroll
        for (int j = 0; j < 2; ++j) {
            acc0 = fmaf(s_q[w][i * 8 + 2 * j],     bf2f((unsigned short)(u[j] & 0xffff)), acc0);
            acc0 = fmaf(s_q[w][i * 8 + 2 * j + 1], bf2f((unsigned short)(u[j] >> 16)),    acc0);
        }
#pragma unroll
        for (int j = 2; j < 4; ++j) {
            acc1 = fmaf(s_q[w][i * 8 + 2 * j],     bf2f((unsigned short)(u[j] & 0xffff)), acc1);
            acc1 = fmaf(s_q[w][i * 8 + 2 * j + 1], bf2f((unsigned short)(u[j] >> 16)),    acc1);
        }
    }
    float acc = (acc0 + acc1) * 0.044194173824159216f;
    float mx = acc;
#pragma unroll
    for (int off = 32; off; off >>= 1) mx = fmaxf(mx, __shfl_xor(mx, off));
    const float e = expf(acc - mx);
    float s = e;
#pragma unroll
    for (int off = 32; off; off >>= 1) s += __shfl_xor(s, off);
    s_a[w][m] = e / s;
    __syncthreads();
    const int c0 = m * 8;
    float av[8];
#pragma unroll
    for (int j = 0; j < 8; ++j) av[j] = 0.f;
    for (int mm = 0; mm < 64; ++mm) {
        const float a = s_a[w][mm];
        const uint4 v = *(const uint4*)(vT + ((size_t)p * 64 + mm) * HIDC + c0);
        const unsigned* u = (const unsigned*)&v;
#pragma unroll
        for (int j = 0; j < 4; ++j) {
            av[2 * j]     = fmaf(a, bf2f((unsigned short)(u[j] & 0xffff)), av[2 * j]);
            av[2 * j + 1] = fmaf(a, bf2f((unsigned short)(u[j] >> 16)),    av[2 * j + 1]);
        }
    }
    float* o = virt + ((size_t)n * 49 + p) * 512 + c0;
    float ps = 0.f, pq = 0.f;
#pragma unroll
    for (int j = 0; j < 8; ++j) {
        o[j] = av[j];
        ps += av[j];
        pq = fmaf(av[j], av[j], pq);
    }
#pragma unroll
    for (int off = 32; off; off >>= 1) {
        ps += __shfl_xor(ps, off);
        pq += __shfl_xor(pq, off);
    }
    if (m == 0) {
        atomicAdd(statsRaw + n * 2, ps);
        atomicAdd(statsRaw + n * 2 + 1, pq);
    }
}

// ---------- fused roi + gap + final fc ----------
__global__ __launch_bounds__(256) void k_gapfinal(
    const float* __restrict__ x, const float* __restrict__ actor,
    const float* __restrict__ wfc1, const float* __restrict__ wfc2,
    float* __restrict__ out)
{
    const int n = blockIdx.x;
    __shared__ float s_h[HIDC], s_r[HIDC];
    const float4* a4 = (const float4*)(actor + (size_t)n * CR);
#pragma unroll
    for (int k = 0; k < 2; ++k) {
        const int h = threadIdx.x + k * 256;
        const float4* w4 = (const float4*)(wfc1 + (size_t)h * CR);
        float ax = 0.f, ay = 0.f, az = 0.f, aw = 0.f;
        for (int i = 0; i < CR / 4; ++i) {
            const float4 a = a4[i], b = w4[i];
            ax = fmaf(a.x, b.x, ax); ay = fmaf(a.y, b.y, ay);
            az = fmaf(a.z, b.z, az); aw = fmaf(a.w, b.w, aw);
        }
        s_r[h] = fmaxf((ax + ay) + (az + aw), 0.f);
        float s0 = 0.f, s1 = 0.f;
        for (int p = 0; p < 48; p += 2) {
            s0 += x[((size_t)n * 49 + p) * 512 + h];
            s1 += x[((size_t)n * 49 + p + 1) * 512 + h];
        }
        s0 += x[((size_t)n * 49 + 48) * 512 + h];
        s_h[h] = (s0 + s1) * (1.f / 49.f);
    }
    __syncthreads();
    const int k = threadIdx.x;
    if (k < NCLS) {
        const float* wr = wfc2 + (size_t)k * (2 * HIDC);
        float acc = 0.f;
        for (int j = 0; j < HIDC; ++j) acc = fmaf(s_r[j], wr[j], acc);
        for (int j = 0; j < HIDC; ++j) acc = fmaf(s_h[j], wr[HIDC + j], acc);
        out[n * NCLS + k] = acc;
    }
}

// ---------------------------------------------------------------------------
extern "C" void kernel_launch(void* const* d_in, const int* in_sizes, int n_in,
                              void* d_out, int out_size, void* d_ws, size_t ws_size,
                              hipStream_t stream) {
    const float* bg    = (const float*)d_in[0];
    const float* actor = (const float*)d_in[1];
    const float* w1    = (const float*)d_in[2];
    const float* w2    = (const float*)d_in[3];
    const float* wq    = (const float*)d_in[4];
    const float* wk    = (const float*)d_in[5];
    const float* wv    = (const float*)d_in[6];
    const float* wo    = (const float*)d_in[7];
    const float* gamma = (const float*)d_in[8];
    const float* beta  = (const float*)d_in[9];
    const float* wfc1  = (const float*)d_in[10];
    const float* wfc2  = (const float*)d_in[11];
    float* out = (float*)d_out;
    float* ws  = (float*)d_ws;

    // ---- fp32 regions ----
    float* A_T   = ws;                        // 131,072
    float* Bp    = A_T + 131072;              // 32,768
    float* xA    = Bp + 32768;                // PLANE
    float* xB    = xA + PLANE;                // PLANE
    float* stats = xB + PLANE;                // 128
    float* fend  = stats + 128;
    // ---- bf16 regions ----
    __bf16* x2h  = (__bf16*)fend;             // 64*196*512 = 6,422,528 halves
    float*  virt = (float*)x2h;               // aliases x2h (dead after pool)
    __bf16* inT2 = x2h + 6422528;             // 256*81*512 = 10,616,832
    __bf16* qkvT = inT2;                      // aliases inT2 (dead after conv2)
    __bf16* inT7 = inT2 + 10616832;           // 64*81*512  = 2,654,208
    __bf16* wAll = inT7 + 2654208;            // 9*4608*512 = 21,233,664
    __bf16* bgT  = wAll + (size_t)9 * OCALL * 512;  // 256*1024 = 262,144

    // 1: weight transpose + inT7 borders + bgT
    k_misc<<<5248, 256, 0, stream>>>(w2, wq, wk, wv, wo, bg, wAll, inT7, bgT);
    // 2: A_T and Bp via MFMA
    k_ab<<<dim3(5, 8), 256, 0, stream>>>(bgT, actor, w1, A_T, Bp);
    // 3: conv2 input planes
    k_prep_in2<<<dim3(256, 3), 256, 0, stream>>>(A_T, Bp, inT2);
    // 4: conv2 (VN4, 512 wgs)
    k_conv_mfma<4, false><<<dim3(64, 8), 256, 0, stream>>>(
        inT2, nullptr, nullptr, nullptr, nullptr, wAll, 0,
        nullptr, nullptr, x2h, nullptr, nullptr, 2);
    // 5: pool + pack + residual
    k_pool_prep<<<64 * 49, 256, 0, stream>>>(x2h, inT7, xA);

    float* xin = xA;
    float* xout = xB;
    for (int d = 0; d < 2; ++d) {
        // 6/9: fused qkv (VN4, 384 wgs), zeroes stats for this layer
        k_conv_mfma<4, false><<<dim3(16, 24), 256, 0, stream>>>(
            inT7, nullptr, nullptr, nullptr, nullptr, wAll, 512 + d * 2048,
            nullptr, nullptr, qkvT, nullptr, stats, 0);
        // 7/10: attention + GN partial stats
        k_attvirt<<<dim3(16, 49), 256, 0, stream>>>(
            qkvT, qkvT + PLANE, qkvT + 2 * PLANE, virt, stats);
        // 8/11: wo conv with fused GN-affine+relu staging (VN2, 256 wgs)
        k_conv_mfma<2, true><<<dim3(32, 8), 256, 0, stream>>>(
            nullptr, virt, stats, gamma + d * HIDC, beta + d * HIDC,
            wAll, 2048 + d * 2048, xin, xout, nullptr,
            d == 0 ? inT7 : nullptr, nullptr, 1);
        float* t = xin; xin = xout; xout = t;
    }
    // 12: roi + gap + final fc
    k_gapfinal<<<64, 256, 0, stream>>>(xin, actor, wfc1, wfc2, out);
}